// Round 5
// baseline (474.223 us; speedup 1.0000x reference)
//
#include <hip/hip_runtime.h>
#include <math.h>

#define D_MODEL 1024
#define TT 4096
#define NB 4
#define NH 16
#define TCH 8

typedef __attribute__((ext_vector_type(8))) short s8v;
typedef __attribute__((ext_vector_type(4))) float f4v;
typedef __attribute__((ext_vector_type(8))) unsigned short u16x8;

// ---- workspace layout (bytes); peak ~88 MB (proven budget 100 MB) ----
#define OFF_STATS ((size_t)0)
#define OFF_GP    ((size_t)(1) << 20)    // 8*64*1024*4 = 2 MB partials
#define OFF_MP    ((size_t)(3) << 20)    // 2 MB
#define OFF_CP    ((size_t)(5) << 20)    // 8*64*2048*4 = 4 MB
#define OFF_FT    ((size_t)(9) << 20)    // 512 KB
#define OFF_WKH   ((size_t)(10) << 20)
#define OFF_WKL   ((size_t)(11) << 20)
#define OFF_WQH   ((size_t)(12) << 20)
#define OFF_WQL   ((size_t)(13) << 20)
#define OFF_WVH   ((size_t)(14) << 20)
#define OFF_WVL   ((size_t)(16) << 20)
#define OFF_WOH   ((size_t)(18) << 20)
#define OFF_WOL   ((size_t)(20) << 20)
#define OFF_Y1    ((size_t)(22) << 20)   // 32 MB
#define OFF_Y2    ((size_t)(54) << 20)   // P*NB*1024*4; FH overlays after build_gmc
#define OFF_FH    OFF_Y2

__device__ __forceinline__ unsigned short bf16_rne(float x) {
  unsigned u = __float_as_uint(x);
  return (unsigned short)((u + 0x7fffu + ((u >> 16) & 1u)) >> 16);
}
__device__ __forceinline__ void split_bf16(float x, unsigned short& h, unsigned short& l) {
  unsigned u = __float_as_uint(x);
  unsigned r = (u + 0x7fffu + ((u >> 16) & 1u)) & 0xffff0000u;
  h = (unsigned short)(r >> 16);
  float res = x - __uint_as_float(r);
  l = bf16_rne(res);
}

// async global->LDS, 16 B per lane; lds base must be wave-uniform (HW adds lane*16)
__device__ __forceinline__ void gll16(unsigned short* lds, const unsigned short* g) {
  __builtin_amdgcn_global_load_lds(
      (__attribute__((address_space(1))) void*)(void*)(g),
      (__attribute__((address_space(3))) void*)(lds), 16, 0, 0);
}

// bijective XCD swizzle: the gx blocks sharing one (y,z) land consecutively on ONE
// XCD; (y,z) values strided by 8 across XCDs (keeps P-masked kernels balanced).
__device__ __forceinline__ void xcd_swz(int gx, int gy, int& x, int& y, int& z) {
  int wg = blockIdx.x + gx * (blockIdx.y + gy * blockIdx.z);
  int k = wg & 7, j = wg >> 3;
  x = j % gx;
  int yz = k + ((j / gx) << 3);
  y = yz % gy;
  z = yz / gy;
}

// ---------------- LayerNorm statistics: one block per row ----------------
__global__ __launch_bounds__(256) void ln_stats_k(const float* __restrict__ X,
                                                  float* __restrict__ stats) {
  int r = blockIdx.x;
  const float4 v = ((const float4*)(X + (size_t)r * D_MODEL))[threadIdx.x];
  float s  = v.x + v.y + v.z + v.w;
  float ss = v.x * v.x + v.y * v.y + v.z * v.z + v.w * v.w;
#pragma unroll
  for (int off = 32; off > 0; off >>= 1) {
    s  += __shfl_down(s, off, 64);
    ss += __shfl_down(ss, off, 64);
  }
  __shared__ float as_[4], bs_[4];
  int w = threadIdx.x >> 6, lane = threadIdx.x & 63;
  if (lane == 0) { as_[w] = s; bs_[w] = ss; }
  __syncthreads();
  if (threadIdx.x == 0) {
    float S  = as_[0] + as_[1] + as_[2] + as_[3];
    float SS = bs_[0] + bs_[1] + bs_[2] + bs_[3];
    float mu  = S * (1.0f / D_MODEL);
    float var = SS * (1.0f / D_MODEL) - mu * mu;
    stats[2 * (size_t)r]     = mu;
    stats[2 * (size_t)r + 1] = 1.0f / sqrtf(var + 1e-5f);
  }
}

// ------- prep: transpose W[K][N] -> WT_hi/lo [N][K] bf16 split -------
// swz=1: XOR-swizzle 16B chunk index with row&7 within each 64-col group
// (consumed by gemm_out_k's linear global_load_lds + swizzled ds_read).
__global__ __launch_bounds__(256) void prep_w_k(const float* __restrict__ W, int N,
                                                unsigned short* __restrict__ Thi,
                                                unsigned short* __restrict__ Tlo,
                                                int swz) {
  __shared__ float tileT[32 * 33];
  const int n0 = blockIdx.x * 32, k0 = blockIdx.y * 32;
  const int tid = threadIdx.x;
  {
    int k_l = tid >> 3, n4 = (tid & 7) << 2;
    float4 v = *(const float4*)&W[(size_t)(k0 + k_l) * N + n0 + n4];
    tileT[(n4 + 0) * 33 + k_l] = v.x;
    tileT[(n4 + 1) * 33 + k_l] = v.y;
    tileT[(n4 + 2) * 33 + k_l] = v.z;
    tileT[(n4 + 3) * 33 + k_l] = v.w;
  }
  __syncthreads();
  {
    int n_l = tid >> 3, k4 = (tid & 7) << 2;
    unsigned short h[4], l[4];
#pragma unroll
    for (int i = 0; i < 4; i++) split_bf16(tileT[n_l * 33 + k4 + i], h[i], l[i]);
    int kc = k0 + k4;
    int col = swz ? ((kc & ~63) | ((((kc >> 3) & 7) ^ (n_l & 7)) << 3) | (kc & 7)) : kc;
    *(ushort4*)&Thi[(size_t)(n0 + n_l) * 1024 + col] = make_ushort4(h[0], h[1], h[2], h[3]);
    *(ushort4*)&Tlo[(size_t)(n0 + n_l) * 1024 + col] = make_ushort4(l[0], l[1], l[2], l[3]);
  }
}

// ------- fused LN + projection GEMM, split-bf16 MFMA (3 products) -------
// 128x256 tile, 512 thr, 8 waves (2M x 4N): halves per-output LN restage cost.
// A reg-staged (LN fusion); B via global_load_lds width-16, linear [256][32] LDS.
// mode 2: rows t<P, Wv -> Y2 compact
__global__ __launch_bounds__(512) void gemm_proj_k(
    const float* __restrict__ X, const float* __restrict__ stats,
    const float* __restrict__ lng, const float* __restrict__ lnb,
    const unsigned short* __restrict__ WThi, const unsigned short* __restrict__ WTlo,
    int Nw, const int* __restrict__ pref, int mode, float* __restrict__ Y) {
  int P = pref[0]; P = P < 1 ? 1 : (P > TT - 1 ? TT - 1 : P);
  int xx, yy, zz;
  xcd_swz(4, 32, xx, yy, zz);
  const int b  = zz;
  const int t0 = yy * 128;
  const int n0 = xx * 256;
  if (mode == 1) { if (t0 + 128 <= P) return; }
  else           { if (t0 >= P) return; }
  const int row0 = b * TT + t0;
  __shared__ __align__(16) unsigned short Ah[128 * 40], Al[128 * 40];
  __shared__ __align__(16) unsigned short Bh[256 * 32], Bl[256 * 32];
  __shared__ float mus[128], rss[128];
  const int tid = threadIdx.x;
  if (tid < 128) {
    mus[tid] = stats[2 * (size_t)(row0 + tid)];
    rss[tid] = stats[2 * (size_t)(row0 + tid) + 1];
  }
  const int lane = tid & 63;
  const int wid  = tid >> 6;
  const int wm = (wid >> 2) * 64, wn = (wid & 3) * 64;
  const int lm = lane & 15, lq = lane >> 4;
  const int srow = lane >> 2, scol = (lane & 3) << 3;  // staging: 16 rows x 4 chunks
  f4v acc[4][4];
#pragma unroll
  for (int i = 0; i < 4; i++)
#pragma unroll
    for (int j = 0; j < 4; j++) acc[i][j] = (f4v){0.f, 0.f, 0.f, 0.f};

  for (int kt = 0; kt < D_MODEL; kt += 32) {
    __syncthreads();
#pragma unroll
    for (int s = 0; s < 2; s++) {
      int seg = wid * 2 + s;
      int brow = n0 + seg * 16 + srow;
      gll16(&Bh[seg * 512], &WThi[(size_t)brow * 1024 + kt + scol]);
      gll16(&Bl[seg * 512], &WTlo[(size_t)brow * 1024 + kt + scol]);
    }
    {
      int m = tid >> 2, k8 = (tid & 3) << 3;
      const float* src = &X[(size_t)(row0 + m) * D_MODEL + kt + k8];
      float mu = mus[m], rs = rss[m];
      u16x8 hv, lv;
#pragma unroll
      for (int i = 0; i < 8; i++) {
        float nv = (src[i] - mu) * rs * lng[kt + k8 + i] + lnb[kt + k8 + i];
        unsigned short h, l;
        split_bf16(nv, h, l);
        hv[i] = h; lv[i] = l;
      }
      *(u16x8*)&Ah[m * 40 + k8] = hv;
      *(u16x8*)&Al[m * 40 + k8] = lv;
    }
    __syncthreads();
    s8v ah[4], al[4], bh[4], bl[4];
#pragma unroll
    for (int i = 0; i < 4; i++) {
      int ar = (wm + i * 16 + lm) * 40 + lq * 8;
      int br = (wn + i * 16 + lm) * 32 + lq * 8;
      ah[i] = *(const s8v*)&Ah[ar];
      al[i] = *(const s8v*)&Al[ar];
      bh[i] = *(const s8v*)&Bh[br];
      bl[i] = *(const s8v*)&Bl[br];
    }
#pragma unroll
    for (int mi = 0; mi < 4; mi++)
#pragma unroll
      for (int ni = 0; ni < 4; ni++) {
        acc[mi][ni] = __builtin_amdgcn_mfma_f32_16x16x32_bf16(ah[mi], bh[ni], acc[mi][ni], 0, 0, 0);
        acc[mi][ni] = __builtin_amdgcn_mfma_f32_16x16x32_bf16(ah[mi], bl[ni], acc[mi][ni], 0, 0, 0);
        acc[mi][ni] = __builtin_amdgcn_mfma_f32_16x16x32_bf16(al[mi], bh[ni], acc[mi][ni], 0, 0, 0);
      }
  }
#pragma unroll
  for (int mi = 0; mi < 4; mi++) {
#pragma unroll
    for (int r = 0; r < 4; r++) {
      int t = t0 + wm + mi * 16 + lq * 4 + r;
      bool ok = (mode == 1) ? (t >= P) : (t < P);
      if (!ok) continue;
      size_t orow = (mode == 2) ? ((size_t)b * P + t) : ((size_t)b * TT + t);
#pragma unroll
      for (int ni = 0; ni < 4; ni++)
        Y[orow * Nw + n0 + wn + ni * 16 + lm] = acc[mi][ni][r];
    }
  }
}

// ------- merged K/Q projection: one launch, 128x256 tile (N=512 -> 2 x-tiles) -------
__global__ __launch_bounds__(512) void gemm_kq_k(
    const float* __restrict__ X, const float* __restrict__ stats,
    const float* __restrict__ lng, const float* __restrict__ lnb,
    const unsigned short* __restrict__ KH, const unsigned short* __restrict__ KL,
    const unsigned short* __restrict__ QH, const unsigned short* __restrict__ QL,
    const int* __restrict__ pref, float* __restrict__ Y) {
  int P = pref[0]; P = P < 1 ? 1 : (P > TT - 1 ? TT - 1 : P);
  int xx, yy, zz;
  xcd_swz(2, 32, xx, yy, zz);
  const int b  = zz;
  const int t0 = yy * 128;
  const int n0 = xx * 256;
  const int row0 = b * TT + t0;
  const bool hasK = (t0 < P);
  const bool hasQ = (t0 + 128 > P);
  __shared__ __align__(16) unsigned short Ah[128 * 40], Al[128 * 40];
  __shared__ __align__(16) unsigned short Bh[256 * 32], Bl[256 * 32];
  __shared__ float mus[128], rss[128];
  const int tid = threadIdx.x;
  if (tid < 128) {
    mus[tid] = stats[2 * (size_t)(row0 + tid)];
    rss[tid] = stats[2 * (size_t)(row0 + tid) + 1];
  }
  const int lane = tid & 63;
  const int wid  = tid >> 6;
  const int wm = (wid >> 2) * 64, wn = (wid & 3) * 64;
  const int lm = lane & 15, lq = lane >> 4;
  const int srow = lane >> 2, scol = (lane & 3) << 3;

  for (int pass = 0; pass < 2; pass++) {
    if (pass == 0 && !hasK) continue;
    if (pass == 1 && !hasQ) continue;
    const unsigned short* WThi = pass ? QH : KH;
    const unsigned short* WTlo = pass ? QL : KL;
    f4v acc[4][4];
#pragma unroll
    for (int i = 0; i < 4; i++)
#pragma unroll
      for (int j = 0; j < 4; j++) acc[i][j] = (f4v){0.f, 0.f, 0.f, 0.f};

    for (int kt = 0; kt < D_MODEL; kt += 32) {
      __syncthreads();
#pragma unroll
      for (int s = 0; s < 2; s++) {
        int seg = wid * 2 + s;
        int brow = n0 + seg * 16 + srow;
        gll16(&Bh[seg * 512], &WThi[(size_t)brow * 1024 + kt + scol]);
        gll16(&Bl[seg * 512], &WTlo[(size_t)brow * 1024 + kt + scol]);
      }
      {
        int m = tid >> 2, k8 = (tid & 3) << 3;
        const float* src = &X[(size_t)(row0 + m) * D_MODEL + kt + k8];
        float mu = mus[m], rs = rss[m];
        u16x8 hv, lv;
#pragma unroll
        for (int i = 0; i < 8; i++) {
          float nv = (src[i] - mu) * rs * lng[kt + k8 + i] + lnb[kt + k8 + i];
          unsigned short h, l;
          split_bf16(nv, h, l);
          hv[i] = h; lv[i] = l;
        }
        *(u16x8*)&Ah[m * 40 + k8] = hv;
        *(u16x8*)&Al[m * 40 + k8] = lv;
      }
      __syncthreads();
      s8v ah[4], al[4], bh[4], bl[4];
#pragma unroll
      for (int i = 0; i < 4; i++) {
        int ar = (wm + i * 16 + lm) * 40 + lq * 8;
        int br = (wn + i * 16 + lm) * 32 + lq * 8;
        ah[i] = *(const s8v*)&Ah[ar];
        al[i] = *(const s8v*)&Al[ar];
        bh[i] = *(const s8v*)&Bh[br];
        bl[i] = *(const s8v*)&Bl[br];
      }
#pragma unroll
      for (int mi = 0; mi < 4; mi++)
#pragma unroll
        for (int ni = 0; ni < 4; ni++) {
          acc[mi][ni] = __builtin_amdgcn_mfma_f32_16x16x32_bf16(ah[mi], bh[ni], acc[mi][ni], 0, 0, 0);
          acc[mi][ni] = __builtin_amdgcn_mfma_f32_16x16x32_bf16(ah[mi], bl[ni], acc[mi][ni], 0, 0, 0);
          acc[mi][ni] = __builtin_amdgcn_mfma_f32_16x16x32_bf16(al[mi], bh[ni], acc[mi][ni], 0, 0, 0);
        }
    }
#pragma unroll
    for (int mi = 0; mi < 4; mi++) {
#pragma unroll
      for (int r = 0; r < 4; r++) {
        int t = t0 + wm + mi * 16 + lq * 4 + r;
        bool ok = pass ? (t >= P) : (t < P);
        if (!ok) continue;
#pragma unroll
        for (int ni = 0; ni < 4; ni++)
          Y[((size_t)b * TT + t) * 512 + n0 + wn + ni * 16 + lm] = acc[mi][ni][r];
      }
    }
  }
}

// ------------- G, M, C_v Gram reductions via MFMA (partials, no atomics) -------------
__global__ __launch_bounds__(256) void build_gmc_mfma_k(
    const float* __restrict__ Y1, const float* __restrict__ Y2,
    const int* __restrict__ pref,
    float* __restrict__ Gp, float* __restrict__ Mp, float* __restrict__ Cp) {
  int P = pref[0]; P = P < 1 ? 1 : (P > TT - 1 ? TT - 1 : P);
  const int c  = blockIdx.x;
  const int bh = blockIdx.y;
  const int b = bh >> 4, h = bh & 15;
  const int chunk = (P + TCH - 1) / TCH;
  const int tb = c * chunk;
  const int te = min(tb + chunk, P);

  __shared__ __align__(16) unsigned short kCh[32 * 136], kCl[32 * 136];
  __shared__ __align__(16) unsigned short kPh[32 * 136], kPl[32 * 136];
  __shared__ __align__(16) unsigned short vTh[64 * 136], vTl[64 * 136];

  const int tid = threadIdx.x;
  const int wid = tid >> 6, lane = tid & 63;
  const int lm = lane & 15, lq = lane >> 4;

  f4v acc[4];
#pragma unroll
  for (int i = 0; i < 4; i++) acc[i] = (f4v){0.f, 0.f, 0.f, 0.f};

  for (int t0 = tb; t0 < te; t0 += 128) {
    const int len = (te - t0 < 128) ? (te - t0) : 128;
    __syncthreads();
    // stage keys: rows 0..128 map t = t0-1+row; kC[u=row-1] current, kP[u=row] prev
    for (int e = tid; e < 129 * 8; e += 256) {
      int row = e >> 3, j4 = (e & 7) << 2;
      int t = t0 - 1 + row;
      float4 kv = make_float4(0.f, 0.f, 0.f, 0.f);
      if (row <= len && t >= 0)
        kv = *(const float4*)&Y1[((size_t)b * TT + t) * 512 + h * 32 + j4];
      unsigned short hh[4], ll[4];
      split_bf16(kv.x, hh[0], ll[0]); split_bf16(kv.y, hh[1], ll[1]);
      split_bf16(kv.z, hh[2], ll[2]); split_bf16(kv.w, hh[3], ll[3]);
      if (row >= 1) {
#pragma unroll
        for (int q = 0; q < 4; q++) {
          kCh[(j4 + q) * 136 + row - 1] = hh[q];
          kCl[(j4 + q) * 136 + row - 1] = ll[q];
        }
      }
      if (row < 128) {
#pragma unroll
        for (int q = 0; q < 4; q++) {
          kPh[(j4 + q) * 136 + row] = hh[q];
          kPl[(j4 + q) * 136 + row] = ll[q];
        }
      }
    }
    // stage values: v_t[d] at u = row
    for (int e = tid; e < 128 * 16; e += 256) {
      int row = e >> 4, dj = (e & 15) << 2;
      int t = t0 + row;
      float4 vv = make_float4(0.f, 0.f, 0.f, 0.f);
      if (row < len)
        vv = *(const float4*)&Y2[((size_t)b * P + t) * 1024 + h * 64 + dj];
      unsigned short hh[4], ll[4];
      split_bf16(vv.x, hh[0], ll[0]); split_bf16(vv.y, hh[1], ll[1]);
      split_bf16(vv.z, hh[2], ll[2]); split_bf16(vv.w, hh[3], ll[3]);
#pragma unroll
      for (int q = 0; q < 4; q++) {
        vTh[(dj + q) * 136 + row] = hh[q];
        vTl[(dj + q) * 136 + row] = ll[q];
      }
    }
    __syncthreads();

#pragma unroll
    for (int kk = 0; kk < 128; kk += 32) {
      const int off = kk + lq * 8;
      if (wid == 0) {
        s8v h0 = *(const s8v*)&kCh[(0 + lm) * 136 + off];
        s8v h1 = *(const s8v*)&kCh[(16 + lm) * 136 + off];
        s8v l0 = *(const s8v*)&kCl[(0 + lm) * 136 + off];
        s8v l1 = *(const s8v*)&kCl[(16 + lm) * 136 + off];
        acc[0] = __builtin_amdgcn_mfma_f32_16x16x32_bf16(h0, h0, acc[0], 0, 0, 0);
        acc[0] = __builtin_amdgcn_mfma_f32_16x16x32_bf16(h0, l0, acc[0], 0, 0, 0);
        acc[0] = __builtin_amdgcn_mfma_f32_16x16x32_bf16(l0, h0, acc[0], 0, 0, 0);
        acc[1] = __builtin_amdgcn_mfma_f32_16x16x32_bf16(h0, h1, acc[1], 0, 0, 0);
        acc[1] = __builtin_amdgcn_mfma_f32_16x16x32_bf16(h0, l1, acc[1], 0, 0, 0);
        acc[1] = __builtin_amdgcn_mfma_f32_16x16x32_bf16(l0, h1, acc[1], 0, 0, 0);
        acc[2] = __builtin_amdgcn_mfma_f32_16x16x32_bf16(h1, h0, acc[2], 0, 0, 0);
        acc[2] = __builtin_amdgcn_mfma_f32_16x16x32_bf16(h1, l0, acc[2], 0, 0, 0);
        acc[2] = __builtin_amdgcn_mfma_f32_16x16x32_bf16(l1, h0, acc[2], 0, 0, 0);
        acc[3] = __builtin_amdgcn_mfma_f32_16x16x32_bf16(h1, h1, acc[3], 0, 0, 0);
        acc[3] = __builtin_amdgcn_mfma_f32_16x16x32_bf16(h1, l1, acc[3], 0, 0, 0);
        acc[3] = __builtin_amdgcn_mfma_f32_16x16x32_bf16(l1, h1, acc[3], 0, 0, 0);
      } else if (wid == 1) {
        s8v ah0 = *(const s8v*)&kCh[(0 + lm) * 136 + off];
        s8v ah1 = *(const s8v*)&kCh[(16 + lm) * 136 + off];
        s8v al0 = *(const s8v*)&kCl[(0 + lm) * 136 + off];
        s8v al1 = *(const s8v*)&kCl[(16 + lm) * 136 + off];
        s8v bh0 = *(const s8v*)&kPh[(0 + lm) * 136 + off];
        s8v bh1 = *(const s8v*)&kPh[(16 + lm) * 136 + off];
        s8v bl0 = *(const s8v*)&kPl[(0 + lm) * 136 + off];
        s8v bl1 = *(const s8v*)&kPl[(16 + lm) * 136 + off];
        acc[0] = __builtin_amdgcn_mfma_f32_16x16x32_bf16(ah0, bh0, acc[0], 0, 0, 0);
        acc[0] = __builtin_amdgcn_mfma_f32_16x16x32_bf16(ah0, bl0, acc[0], 0, 0, 0);
        acc[0] = __builtin_amdgcn_mfma_f32_16x16x32_bf16(al0, bh0, acc[0], 0, 0, 0);
        acc[1] = __builtin_amdgcn_mfma_f32_16x16x32_bf16(ah0, bh1, acc[1], 0, 0, 0);
        acc[1] = __builtin_amdgcn_mfma_f32_16x16x32_bf16(ah0, bl1, acc[1], 0, 0, 0);
        acc[1] = __builtin_amdgcn_mfma_f32_16x16x32_bf16(al0, bh1, acc[1], 0, 0, 0);
        acc[2] = __builtin_amdgcn_mfma_f32_16x16x32_bf16(ah1, bh0, acc[2], 0, 0, 0);
        acc[2] = __builtin_amdgcn_mfma_f32_16x16x32_bf16(ah1, bl0, acc[2], 0, 0, 0);
        acc[2] = __builtin_amdgcn_mfma_f32_16x16x32_bf16(al1, bh0, acc[2], 0, 0, 0);
        acc[3] = __builtin_amdgcn_mfma_f32_16x16x32_bf16(ah1, bh1, acc[3], 0, 0, 0);
        acc[3] = __builtin_amdgcn_mfma_f32_16x16x32_bf16(ah1, bl1, acc[3], 0, 0, 0);
        acc[3] = __builtin_amdgcn_mfma_f32_16x16x32_bf16(al1, bh1, acc[3], 0, 0, 0);
      } else {
        const int d0 = (wid - 2) * 32;
        s8v vh0 = *(const s8v*)&vTh[(d0 + lm) * 136 + off];
        s8v vh1 = *(const s8v*)&vTh[(d0 + 16 + lm) * 136 + off];
        s8v vl0 = *(const s8v*)&vTl[(d0 + lm) * 136 + off];
        s8v vl1 = *(const s8v*)&vTl[(d0 + 16 + lm) * 136 + off];
        s8v kh0 = *(const s8v*)&kCh[(0 + lm) * 136 + off];
        s8v kh1 = *(const s8v*)&kCh[(16 + lm) * 136 + off];
        s8v kl0 = *(const s8v*)&kCl[(0 + lm) * 136 + off];
        s8v kl1 = *(const s8v*)&kCl[(16 + lm) * 136 + off];
        acc[0] = __builtin_amdgcn_mfma_f32_16x16x32_bf16(vh0, kh0, acc[0], 0, 0, 0);
        acc[0] = __builtin_amdgcn_mfma_f32_16x16x32_bf16(vh0, kl0, acc[0], 0, 0, 0);
        acc[0] = __builtin_amdgcn_mfma_f32_16x16x32_bf16(vl0, kh0, acc[0], 0, 0, 0);
        acc[1] = __builtin_amdgcn_mfma_f32_16x16x32_bf16(vh0, kh1, acc[1], 0, 0, 0);
        acc[1] = __builtin_amdgcn_mfma_f32_16x16x32_bf16(vh0, kl1, acc[1], 0, 0, 0);
        acc[1] = __builtin_amdgcn_mfma_f32_16x16x32_bf16(vl0, kh1, acc[1], 0, 0, 0);
        acc[2] = __builtin_amdgcn_mfma_f32_16x16x32_bf16(vh1, kh0, acc[2], 0, 0, 0);
        acc[2] = __builtin_amdgcn_mfma_f32_16x16x32_bf16(vh1, kl0, acc[2], 0, 0, 0);
        acc[2] = __builtin_amdgcn_mfma_f32_16x16x32_bf16(vl1, kh0, acc[2], 0, 0, 0);
        acc[3] = __builtin_amdgcn_mfma_f32_16x16x32_bf16(vh1, kh1, acc[3], 0, 0, 0);
        acc[3] = __builtin_amdgcn_mfma_f32_16x16x32_bf16(vh1, kl1, acc[3], 0, 0, 0);
        acc[3] = __builtin_amdgcn_mfma_f32_16x16x32_bf16(vl1, kh1, acc[3], 0, 0, 0);
      }
    }
  }

  // write partials (D layout: col = lm, row = lq*4 + r)
  if (wid < 2) {
    float* dst = (wid == 0 ? Gp : Mp) + (size_t)(c * 64 + bh) * 1024;
#pragma unroll
    for (int t = 0; t < 4; t++) {
      int i0 = (t >> 1) * 16, j0 = (t & 1) * 16;
#pragma unroll
      for (int r = 0; r < 4; r++)
        dst[(i0 + lq * 4 + r) * 32 + j0 + lm] = acc[t][r];
    }
  } else {
    float* dst = Cp + (size_t)(c * 64 + bh) * 2048;
#pragma unroll
    for (int t = 0; t < 4; t++) {
      int d0 = (wid - 2) * 32 + (t >> 1) * 16, j0 = (t & 1) * 16;
#pragma unroll
      for (int r = 0; r < 4; r++)
        dst[(d0 + lq * 4 + r) * 32 + j0 + lm] = acc[t][r];
    }
  }
}

// ------- per-(b,h) operator: chol, G^{-1}, A_w, sigma, F = Cv*Gi*(s*M*Gi)^4 -------
__global__ __launch_bounds__(256) void solve_op_k(
    const float* __restrict__ Gp, const float* __restrict__ Mp,
    const float* __restrict__ Cp, const float* __restrict__ lridge,
    const float* __restrict__ lgamma, float* __restrict__ Ft) {
  __shared__ float Gs[32 * 33];
  __shared__ float Ms[32 * 32];
  __shared__ float Gi[32 * 32];
  __shared__ float W1[32 * 33];
  __shared__ float Aw[32 * 33];
  __shared__ float Nn[32 * 32];
  __shared__ float N2[32 * 32];
  __shared__ float T1[32 * 32];
  __shared__ float Cs[64 * 32];
  __shared__ float red[256];
  const int bh = blockIdx.x;
  const int tid = threadIdx.x;
  const float ridge = expf(lridge[0]);

  for (int e = tid; e < 1024; e += 256) {
    int i = e >> 5, j = e & 31;
    float g = 0.f, m = 0.f;
#pragma unroll
    for (int cc = 0; cc < TCH; cc++) {
      g += Gp[(size_t)(cc * 64 + bh) * 1024 + e];
      m += Mp[(size_t)(cc * 64 + bh) * 1024 + e];
    }
    if (i == j) g += ridge;
    Gs[i * 33 + j] = g;
    Ms[e] = m;
  }
  for (int e = tid; e < 2048; e += 256) {
    float s = 0.f;
#pragma unroll
    for (int cc = 0; cc < TCH; cc++) s += Cp[(size_t)(cc * 64 + bh) * 2048 + e];
    Cs[e] = s;
  }
  __syncthreads();

  for (int j = 0; j < 32; j++) {
    float d = Gs[j * 33 + j];
    __syncthreads();
    float inv = 1.0f / sqrtf(d);
    if (tid >= j && tid < 32) Gs[tid * 33 + j] *= inv;
    __syncthreads();
    int w = 31 - j;
    for (int e = tid; e < w * w; e += 256) {
      int i = j + 1 + e / w, k = j + 1 + e % w;
      Gs[i * 33 + k] -= Gs[i * 33 + j] * Gs[k * 33 + j];
    }
    __syncthreads();
  }

  if (tid < 32) {
    const int c = tid;
    for (int i = 0; i < 32; i++) W1[i * 33 + c] = (i == c) ? 1.0f : 0.0f;
    for (int i = 0; i < 32; i++) {
      float s = W1[i * 33 + c];
      for (int j = 0; j < i; j++) s -= Gs[i * 33 + j] * W1[j * 33 + c];
      W1[i * 33 + c] = s / Gs[i * 33 + i];
    }
    for (int i = 31; i >= 0; i--) {
      float s = W1[i * 33 + c];
      for (int j = i + 1; j < 32; j++) s -= Gs[j * 33 + i] * W1[j * 33 + c];
      W1[i * 33 + c] = s / Gs[i * 33 + i];
    }
    for (int i = 0; i < 32; i++) Gi[i * 32 + c] = W1[i * 33 + c];
  }
  __syncthreads();
  if (tid < 32) {
    const int c = tid;
    for (int i = 0; i < 32; i++) {
      float s = Ms[i * 32 + c];
      for (int j = 0; j < i; j++) s -= Gs[i * 33 + j] * W1[j * 33 + c];
      W1[i * 33 + c] = s / Gs[i * 33 + i];
    }
  }
  __syncthreads();
  if (tid < 32) {
    const int c = tid;
    for (int i = 0; i < 32; i++) {
      float s = W1[c * 33 + i];
      for (int j = 0; j < i; j++) s -= Gs[i * 33 + j] * Aw[j * 33 + c];
      Aw[i * 33 + c] = s / Gs[i * 33 + i];
    }
  }
  __syncthreads();

  float s0 = 0.0f;
  for (int e = tid; e < 1024; e += 256) {
    float a = Aw[(e >> 5) * 33 + (e & 31)];
    s0 += a * a;
  }
  red[tid] = s0;
  __syncthreads();
  for (int off = 128; off > 0; off >>= 1) {
    if (tid < off) red[tid] += red[tid + off];
    __syncthreads();
  }
  float frob2 = red[0];
  float sigma;
  if (frob2 <= 1.0f) {
    sigma = sqrtf(frob2);
  } else {
    // barrier-free power iteration in wave 0: lane pairs (i, i+32) mirror lane i<32.
    // lane holds row i of Aw and row i of Aw^T in registers; matvec = 32 shfl-FMA;
    // norms = shfl_xor tree within each 32-lane half. Same math/start/sequence as
    // the block version; early exit when sigma converged (<1e-7 rel, sub-tolerance).
    __syncthreads();
    if (tid < 64) {
      const int i = tid & 31;
      float ar[32], at[32];
#pragma unroll
      for (int j = 0; j < 32; j++) { ar[j] = Aw[i * 33 + j]; at[j] = Aw[j * 33 + i]; }
      float v = 1.0f + 0.001f * (float)i;
      float sig = 0.0f, prev = -1.0f;
      for (int it = 0; it < 64; it++) {
        float u = 0.0f;
#pragma unroll
        for (int j = 0; j < 32; j++) u += ar[j] * __shfl(v, j, 64);
        float nu2 = u * u;
#pragma unroll
        for (int off = 16; off > 0; off >>= 1) nu2 += __shfl_xor(nu2, off, 64);
        u /= fmaxf(sqrtf(nu2), 1e-30f);
        float vn = 0.0f;
#pragma unroll
        for (int j = 0; j < 32; j++) vn += at[j] * __shfl(u, j, 64);
        float nv2 = vn * vn;
#pragma unroll
        for (int off = 16; off > 0; off >>= 1) nv2 += __shfl_xor(nv2, off, 64);
        sig = sqrtf(nv2);
        v = vn / fmaxf(sig, 1e-30f);
        if (it >= 7 && fabsf(sig - prev) <= 1e-7f * sig) break;
        prev = sig;
      }
      if (tid == 0) red[0] = sig;
    }
    __syncthreads();
    sigma = red[0];
  }
  float gamma_c = fminf(expf(lgamma[0]), 1.0f);
  float scale = gamma_c / fmaxf(fmaxf(sigma, 1e-8f), 1.0f);

  for (int e = tid; e < 1024; e += 256) {
    int i = e >> 5, c = e & 31;
    float s = 0;
#pragma unroll
    for (int k = 0; k < 32; k++) s += Ms[i * 32 + k] * Gi[k * 32 + c];
    Nn[e] = scale * s;
  }
  __syncthreads();
  for (int e = tid; e < 1024; e += 256) {
    int i = e >> 5, c = e & 31;
    float s = 0;
#pragma unroll
    for (int k = 0; k < 32; k++) s += Nn[i * 32 + k] * Nn[k * 32 + c];
    N2[e] = s;
  }
  __syncthreads();
  for (int e = tid; e < 1024; e += 256) {
    int i = e >> 5, c = e & 31;
    float s = 0;
#pragma unroll
    for (int k = 0; k < 32; k++) s += N2[i * 32 + k] * N2[k * 32 + c];
    Ms[e] = s;
  }
  __syncthreads();
  for (int e = tid; e < 1024; e += 256) {
    int i = e >> 5, c = e & 31;
    float s = 0;
#pragma unroll
    for (int k = 0; k < 32; k++) s += Gi[i * 32 + k] * Ms[k * 32 + c];
    T1[e] = s;
  }
  __syncthreads();
  for (int e = tid; e < 2048; e += 256) {
    int j = e >> 6, d = e & 63;
    float s = 0;
#pragma unroll
    for (int k = 0; k < 32; k++) s += Cs[d * 32 + k] * T1[k * 32 + j];
    Ft[(size_t)bh * 2048 + e] = s;
  }
}

// ------------- apply F^T per (head, 128-token chunk) -> full_hi (bf16) -------------
// FH written chunk-swizzled within each head's 64-col group (gemm_out consumes).
__global__ __launch_bounds__(256) void apply_k(const float* __restrict__ Y1,
                                               const float* __restrict__ Ft,
                                               unsigned short* __restrict__ FH) {
  __shared__ float xs[128 * 32];
  const int h = blockIdx.y;
  const int r0 = blockIdx.x * 128;
  const int bh = (r0 >> 12) * NH + h;
  const int tid = threadIdx.x;
  const int d = tid & 63, t0 = tid >> 6;
  float fcol[32];
  const float* fb = &Ft[(size_t)bh * 2048 + d];
#pragma unroll
  for (int j = 0; j < 32; j++) fcol[j] = fb[j * 64];
  for (int e = tid; e < 1024; e += 256) {
    int row = e >> 3, j4 = (e & 7) << 2;
    *(float4*)&xs[row * 32 + j4] =
        *(const float4*)&Y1[((size_t)(r0 + row)) * 512 + h * 32 + j4];
  }
  __syncthreads();
  const int dq = d >> 3, dr = d & 7;
  for (int tl = t0; tl < 128; tl += 4) {
    float s = 0;
#pragma unroll
    for (int j = 0; j < 32; j++) s += xs[tl * 32 + j] * fcol[j];
    int col = h * 64 + ((dq ^ (tl & 7)) << 3) + dr;
    FH[((size_t)(r0 + tl)) * 1024 + col] = bf16_rne(s);
  }
}

// ------------- output GEMM (MFMA): out = sg * full @ Wo ; A=hi, B=hi+lo -------------
// 256x128 tile, BK=64, 8 waves, double-buffered LDS, counted vmcnt (never 0 in
// steady state), pre-swizzled-global + swizzled ds_read (bank-floor reads).
__global__ __launch_bounds__(512) void gemm_out_k(
    const unsigned short* __restrict__ FH,
    const unsigned short* __restrict__ WThi, const unsigned short* __restrict__ WTlo,
    const float* __restrict__ alpha, float* __restrict__ out) {
  __shared__ __align__(16) unsigned short lds[65536];  // 128 KB: A 2x32K, Bh 2x16K, Bl 2x16K
  int xx, yy, zz;
  xcd_swz(8, 64, xx, yy, zz);
  const int m0 = yy * 256;
  const int n0 = xx * 128;
  const int tid = threadIdx.x;
  const int lane = tid & 63;
  const int wid  = tid >> 6;                 // 0..7
  const int wm = (wid >> 1) * 64;            // 4 M-waves x 64 rows
  const int wn = (wid & 1) * 64;             // 2 N-waves x 64 cols
  const int lm = lane & 15, lq = lane >> 4;
  const int l8 = lane >> 3, c8 = (lane & 7) << 3;  // staging: 8 rows x 8 chunks per issue

  f4v acc[4][4];
#pragma unroll
  for (int i = 0; i < 4; i++)
#pragma unroll
    for (int j = 0; j < 4; j++) acc[i][j] = (f4v){0.f, 0.f, 0.f, 0.f};

  auto STAGE = [&](int t, int buf) {
    const int kt = t * 64;
#pragma unroll
    for (int i = 0; i < 4; i++) {            // A: 4 issues/wave (32 total)
      int iss = wid * 4 + i;
      gll16(&lds[buf * 16384 + iss * 512],
            &FH[(size_t)(m0 + iss * 8 + l8) * 1024 + kt + c8]);
    }
#pragma unroll
    for (int i = 0; i < 2; i++) {            // Bh: 2 issues/wave (16 total)
      int iss = wid * 2 + i;
      gll16(&lds[32768 + buf * 8192 + iss * 512],
            &WThi[(size_t)(n0 + iss * 8 + l8) * 1024 + kt + c8]);
    }
#pragma unroll
    for (int i = 0; i < 2; i++) {            // Bl
      int iss = wid * 2 + i;
      gll16(&lds[49152 + buf * 8192 + iss * 512],
            &WTlo[(size_t)(n0 + iss * 8 + l8) * 1024 + kt + c8]);
    }
  };

  STAGE(0, 0);
  STAGE(1, 1);

  for (int t = 0; t < 16; t++) {
    const int buf = t & 1;
    if (t < 15) asm volatile("s_waitcnt vmcnt(8)" ::: "memory");
    else        asm volatile("s_waitcnt vmcnt(0)" ::: "memory");
    __builtin_amdgcn_s_barrier();
    const unsigned short* Ab  = &lds[buf * 16384];
    const unsigned short* Bhb = &lds[32768 + buf * 8192];
    const unsigned short* Blb = &lds[49152 + buf * 8192];
    __builtin_amdgcn_s_setprio(1);
#pragma unroll
    for (int kk = 0; kk < 2; kk++) {
      s8v ah[4], bh[4], bl[4];
#pragma unroll
      for (int i = 0; i < 4; i++) {
        int rA = wm + i * 16 + lm;
        int rB = wn + i * 16 + lm;
        int sA = (((kk * 4 + lq) ^ (rA & 7)) << 3);
        int sB = (((kk * 4 + lq) ^ (rB & 7)) << 3);
        ah[i] = *(const s8v*)&Ab[rA * 64 + sA];
        bh[i] = *(const s8v*)&Bhb[rB * 64 + sB];
        bl[i] = *(const s8v*)&Blb[rB * 64 + sB];
      }
#pragma unroll
      for (int mi = 0; mi < 4; mi++)
#pragma unroll
        for (int ni = 0; ni < 4; ni++) {
          acc[mi][ni] = __builtin_amdgcn_mfma_f32_16x16x32_bf16(ah[mi], bh[ni], acc[mi][ni], 0, 0, 0);
          acc[mi][ni] = __builtin_amdgcn_mfma_f32_16x16x32_bf16(ah[mi], bl[ni], acc[mi][ni], 0, 0, 0);
        }
    }
    __builtin_amdgcn_s_setprio(0);
    __builtin_amdgcn_sched_barrier(0);
    __builtin_amdgcn_s_barrier();
    if (t < 14) STAGE(t + 2, buf);
  }

  float sg = 1.0f / (1.0f + expf(-alpha[0]));
#pragma unroll
  for (int mi = 0; mi < 4; mi++)
#pragma unroll
    for (int r = 0; r < 4; r++) {
      size_t orow = (size_t)(m0 + wm + mi * 16 + lq * 4 + r);
#pragma unroll
      for (int ni = 0; ni < 4; ni++)
        out[orow * 1024 + n0 + wn + ni * 16 + lm] = sg * acc[mi][ni][r];
    }
}

extern "C" void kernel_launch(void* const* d_in, const int* in_sizes, int n_in,
                              void* d_out, int out_size, void* d_ws, size_t ws_size,
                              hipStream_t stream) {
  const float* X      = (const float*)d_in[0];
  const float* Wk     = (const float*)d_in[1];
  const float* Wq     = (const float*)d_in[2];
  const float* Wv     = (const float*)d_in[3];
  const float* Wo     = (const float*)d_in[4];
  const float* lng    = (const float*)d_in[5];
  const float* lnb    = (const float*)d_in[6];
  const float* alpha  = (const float*)d_in[7];
  const float* lridge = (const float*)d_in[8];
  const float* lgamma = (const float*)d_in[9];
  const int*   pref   = (const int*)d_in[10];
  float* out = (float*)d_out;
  char* ws = (char*)d_ws;
  float* stats = (float*)(ws + OFF_STATS);
  float* Gp    = (float*)(ws + OFF_GP);
  float* Mp    = (float*)(ws + OFF_MP);
  float* Cp    = (float*)(ws + OFF_CP);
  float* Ft    = (float*)(ws + OFF_FT);
  unsigned short* WKH = (unsigned short*)(ws + OFF_WKH);
  unsigned short* WKL = (unsigned short*)(ws + OFF_WKL);
  unsigned short* WQH = (unsigned short*)(ws + OFF_WQH);
  unsigned short* WQL = (unsigned short*)(ws + OFF_WQL);
  unsigned short* WVH = (unsigned short*)(ws + OFF_WVH);
  unsigned short* WVL = (unsigned short*)(ws + OFF_WVL);
  unsigned short* WOH = (unsigned short*)(ws + OFF_WOH);
  unsigned short* WOL = (unsigned short*)(ws + OFF_WOL);
  float* Y1 = (float*)(ws + OFF_Y1);
  float* Y2 = (float*)(ws + OFF_Y2);
  unsigned short* FH = (unsigned short*)(ws + OFF_FH);

  ln_stats_k<<<16384, 256, 0, stream>>>(X, stats);
  prep_w_k<<<dim3(16, 32), 256, 0, stream>>>(Wk, 512, WKH, WKL, 0);
  prep_w_k<<<dim3(16, 32), 256, 0, stream>>>(Wq, 512, WQH, WQL, 0);
  prep_w_k<<<dim3(32, 32), 256, 0, stream>>>(Wv, 1024, WVH, WVL, 0);
  prep_w_k<<<dim3(32, 32), 256, 0, stream>>>(Wo, 1024, WOH, WOL, 1);
  gemm_kq_k<<<dim3(2, 32, NB), 512, 0, stream>>>(X, stats, lng, lnb, WKH, WKL, WQH, WQL, pref, Y1);
  gemm_proj_k<<<dim3(4, 32, NB), 512, 0, stream>>>(X, stats, lng, lnb, WVH, WVL, 1024, pref, 2, Y2);
  build_gmc_mfma_k<<<dim3(TCH, 64), 256, 0, stream>>>(Y1, Y2, pref, Gp, Mp, Cp);
  solve_op_k<<<64, 256, 0, stream>>>(Gp, Mp, Cp, lridge, lgamma, Ft);
  apply_k<<<dim3(128, NH), 256, 0, stream>>>(Y1, Ft, FH);
  gemm_out_k<<<dim3(8, 64), 512, 0, stream>>>(FH, WOH, WOL, alpha, out);
}

// Round 7
// 437.744 us; speedup vs baseline: 1.0833x; 1.0833x over previous
//
#include <hip/hip_runtime.h>
#include <math.h>

#define D_MODEL 1024
#define TT 4096
#define NB 4
#define NH 16
#define TCH 8

typedef __attribute__((ext_vector_type(8))) short s8v;
typedef __attribute__((ext_vector_type(4))) float f4v;
typedef __attribute__((ext_vector_type(8))) unsigned short u16x8;

// ---- workspace layout (bytes); peak ~88 MB (proven budget 100 MB) ----
#define OFF_STATS ((size_t)0)
#define OFF_GP    ((size_t)(1) << 20)    // 8*64*1024*4 = 2 MB partials
#define OFF_MP    ((size_t)(3) << 20)    // 2 MB
#define OFF_CP    ((size_t)(5) << 20)    // 8*64*2048*4 = 4 MB
#define OFF_FT    ((size_t)(9) << 20)    // 512 KB
#define OFF_WKH   ((size_t)(10) << 20)
#define OFF_WKL   ((size_t)(11) << 20)
#define OFF_WQH   ((size_t)(12) << 20)
#define OFF_WQL   ((size_t)(13) << 20)
#define OFF_WVH   ((size_t)(14) << 20)
#define OFF_WVL   ((size_t)(16) << 20)
#define OFF_WOH   ((size_t)(18) << 20)
#define OFF_WOL   ((size_t)(20) << 20)
#define OFF_Y1    ((size_t)(22) << 20)   // 32 MB
#define OFF_Y2    ((size_t)(54) << 20)   // P*NB*1024*4; FH overlays after build_gmc
#define OFF_FH    OFF_Y2

__device__ __forceinline__ unsigned short bf16_rne(float x) {
  unsigned u = __float_as_uint(x);
  return (unsigned short)((u + 0x7fffu + ((u >> 16) & 1u)) >> 16);
}
__device__ __forceinline__ void split_bf16(float x, unsigned short& h, unsigned short& l) {
  unsigned u = __float_as_uint(x);
  unsigned r = (u + 0x7fffu + ((u >> 16) & 1u)) & 0xffff0000u;
  h = (unsigned short)(r >> 16);
  float res = x - __uint_as_float(r);
  l = bf16_rne(res);
}

// async global->LDS, 16 B per lane; lds base must be wave-uniform (HW adds lane*16)
__device__ __forceinline__ void gll16(unsigned short* lds, const unsigned short* g) {
  __builtin_amdgcn_global_load_lds(
      (__attribute__((address_space(1))) void*)(void*)(g),
      (__attribute__((address_space(3))) void*)(lds), 16, 0, 0);
}

// bijective XCD swizzle: the gx blocks sharing one (y,z) land consecutively on ONE
// XCD; (y,z) values strided by 8 across XCDs (keeps P-masked kernels balanced).
__device__ __forceinline__ void xcd_swz(int gx, int gy, int& x, int& y, int& z) {
  int wg = blockIdx.x + gx * (blockIdx.y + gy * blockIdx.z);
  int k = wg & 7, j = wg >> 3;
  x = j % gx;
  int yz = k + ((j / gx) << 3);
  y = yz % gy;
  z = yz / gy;
}

// ---------------- LayerNorm statistics: one block per row ----------------
__global__ __launch_bounds__(256) void ln_stats_k(const float* __restrict__ X,
                                                  float* __restrict__ stats) {
  int r = blockIdx.x;
  const float4 v = ((const float4*)(X + (size_t)r * D_MODEL))[threadIdx.x];
  float s  = v.x + v.y + v.z + v.w;
  float ss = v.x * v.x + v.y * v.y + v.z * v.z + v.w * v.w;
#pragma unroll
  for (int off = 32; off > 0; off >>= 1) {
    s  += __shfl_down(s, off, 64);
    ss += __shfl_down(ss, off, 64);
  }
  __shared__ float as_[4], bs_[4];
  int w = threadIdx.x >> 6, lane = threadIdx.x & 63;
  if (lane == 0) { as_[w] = s; bs_[w] = ss; }
  __syncthreads();
  if (threadIdx.x == 0) {
    float S  = as_[0] + as_[1] + as_[2] + as_[3];
    float SS = bs_[0] + bs_[1] + bs_[2] + bs_[3];
    float mu  = S * (1.0f / D_MODEL);
    float var = SS * (1.0f / D_MODEL) - mu * mu;
    stats[2 * (size_t)r]     = mu;
    stats[2 * (size_t)r + 1] = 1.0f / sqrtf(var + 1e-5f);
  }
}

// ------- prep: transpose W[K][N] -> WT_hi/lo [N][K] bf16 split -------
// swz=1: XOR-swizzle 16B chunk index with row&7 within each 64-col group
// (consumed by gemm_out_k's linear global_load_lds + swizzled ds_read).
__global__ __launch_bounds__(256) void prep_w_k(const float* __restrict__ W, int N,
                                                unsigned short* __restrict__ Thi,
                                                unsigned short* __restrict__ Tlo,
                                                int swz) {
  __shared__ float tileT[32 * 33];
  const int n0 = blockIdx.x * 32, k0 = blockIdx.y * 32;
  const int tid = threadIdx.x;
  {
    int k_l = tid >> 3, n4 = (tid & 7) << 2;
    float4 v = *(const float4*)&W[(size_t)(k0 + k_l) * N + n0 + n4];
    tileT[(n4 + 0) * 33 + k_l] = v.x;
    tileT[(n4 + 1) * 33 + k_l] = v.y;
    tileT[(n4 + 2) * 33 + k_l] = v.z;
    tileT[(n4 + 3) * 33 + k_l] = v.w;
  }
  __syncthreads();
  {
    int n_l = tid >> 3, k4 = (tid & 7) << 2;
    unsigned short h[4], l[4];
#pragma unroll
    for (int i = 0; i < 4; i++) split_bf16(tileT[n_l * 33 + k4 + i], h[i], l[i]);
    int kc = k0 + k4;
    int col = swz ? ((kc & ~63) | ((((kc >> 3) & 7) ^ (n_l & 7)) << 3) | (kc & 7)) : kc;
    *(ushort4*)&Thi[(size_t)(n0 + n_l) * 1024 + col] = make_ushort4(h[0], h[1], h[2], h[3]);
    *(ushort4*)&Tlo[(size_t)(n0 + n_l) * 1024 + col] = make_ushort4(l[0], l[1], l[2], l[3]);
  }
}

// ------- fused LN + projection GEMM, split-bf16 MFMA (3 products) -------
// 128x256 tile, 512 thr, 8 waves (2M x 4N): halves per-output LN restage cost.
// A reg-staged (LN fusion); B via global_load_lds width-16, linear [256][32] LDS.
// mode 2: rows t<P, Wv -> Y2 compact
__global__ __launch_bounds__(512) void gemm_proj_k(
    const float* __restrict__ X, const float* __restrict__ stats,
    const float* __restrict__ lng, const float* __restrict__ lnb,
    const unsigned short* __restrict__ WThi, const unsigned short* __restrict__ WTlo,
    int Nw, const int* __restrict__ pref, int mode, float* __restrict__ Y) {
  int P = pref[0]; P = P < 1 ? 1 : (P > TT - 1 ? TT - 1 : P);
  int xx, yy, zz;
  xcd_swz(4, 32, xx, yy, zz);
  const int b  = zz;
  const int t0 = yy * 128;
  const int n0 = xx * 256;
  if (mode == 1) { if (t0 + 128 <= P) return; }
  else           { if (t0 >= P) return; }
  const int row0 = b * TT + t0;
  __shared__ __align__(16) unsigned short Ah[128 * 40], Al[128 * 40];
  __shared__ __align__(16) unsigned short Bh[256 * 32], Bl[256 * 32];
  __shared__ float mus[128], rss[128];
  const int tid = threadIdx.x;
  if (tid < 128) {
    mus[tid] = stats[2 * (size_t)(row0 + tid)];
    rss[tid] = stats[2 * (size_t)(row0 + tid) + 1];
  }
  const int lane = tid & 63;
  const int wid  = tid >> 6;
  const int wm = (wid >> 2) * 64, wn = (wid & 3) * 64;
  const int lm = lane & 15, lq = lane >> 4;
  const int srow = lane >> 2, scol = (lane & 3) << 3;  // staging: 16 rows x 4 chunks
  f4v acc[4][4];
#pragma unroll
  for (int i = 0; i < 4; i++)
#pragma unroll
    for (int j = 0; j < 4; j++) acc[i][j] = (f4v){0.f, 0.f, 0.f, 0.f};

  for (int kt = 0; kt < D_MODEL; kt += 32) {
    __syncthreads();
#pragma unroll
    for (int s = 0; s < 2; s++) {
      int seg = wid * 2 + s;
      int brow = n0 + seg * 16 + srow;
      gll16(&Bh[seg * 512], &WThi[(size_t)brow * 1024 + kt + scol]);
      gll16(&Bl[seg * 512], &WTlo[(size_t)brow * 1024 + kt + scol]);
    }
    {
      int m = tid >> 2, k8 = (tid & 3) << 3;
      const float* src = &X[(size_t)(row0 + m) * D_MODEL + kt + k8];
      float mu = mus[m], rs = rss[m];
      u16x8 hv, lv;
#pragma unroll
      for (int i = 0; i < 8; i++) {
        float nv = (src[i] - mu) * rs * lng[kt + k8 + i] + lnb[kt + k8 + i];
        unsigned short h, l;
        split_bf16(nv, h, l);
        hv[i] = h; lv[i] = l;
      }
      *(u16x8*)&Ah[m * 40 + k8] = hv;
      *(u16x8*)&Al[m * 40 + k8] = lv;
    }
    __syncthreads();
    s8v ah[4], al[4], bh[4], bl[4];
#pragma unroll
    for (int i = 0; i < 4; i++) {
      int ar = (wm + i * 16 + lm) * 40 + lq * 8;
      int br = (wn + i * 16 + lm) * 32 + lq * 8;
      ah[i] = *(const s8v*)&Ah[ar];
      al[i] = *(const s8v*)&Al[ar];
      bh[i] = *(const s8v*)&Bh[br];
      bl[i] = *(const s8v*)&Bl[br];
    }
#pragma unroll
    for (int mi = 0; mi < 4; mi++)
#pragma unroll
      for (int ni = 0; ni < 4; ni++) {
        acc[mi][ni] = __builtin_amdgcn_mfma_f32_16x16x32_bf16(ah[mi], bh[ni], acc[mi][ni], 0, 0, 0);
        acc[mi][ni] = __builtin_amdgcn_mfma_f32_16x16x32_bf16(ah[mi], bl[ni], acc[mi][ni], 0, 0, 0);
        acc[mi][ni] = __builtin_amdgcn_mfma_f32_16x16x32_bf16(al[mi], bh[ni], acc[mi][ni], 0, 0, 0);
      }
  }
#pragma unroll
  for (int mi = 0; mi < 4; mi++) {
#pragma unroll
    for (int r = 0; r < 4; r++) {
      int t = t0 + wm + mi * 16 + lq * 4 + r;
      bool ok = (mode == 1) ? (t >= P) : (t < P);
      if (!ok) continue;
      size_t orow = (mode == 2) ? ((size_t)b * P + t) : ((size_t)b * TT + t);
#pragma unroll
      for (int ni = 0; ni < 4; ni++)
        Y[orow * Nw + n0 + wn + ni * 16 + lm] = acc[mi][ni][r];
    }
  }
}

// ------- merged K/Q projection: one launch, 128x256 tile (N=512 -> 2 x-tiles) -------
__global__ __launch_bounds__(512) void gemm_kq_k(
    const float* __restrict__ X, const float* __restrict__ stats,
    const float* __restrict__ lng, const float* __restrict__ lnb,
    const unsigned short* __restrict__ KH, const unsigned short* __restrict__ KL,
    const unsigned short* __restrict__ QH, const unsigned short* __restrict__ QL,
    const int* __restrict__ pref, float* __restrict__ Y) {
  int P = pref[0]; P = P < 1 ? 1 : (P > TT - 1 ? TT - 1 : P);
  int xx, yy, zz;
  xcd_swz(2, 32, xx, yy, zz);
  const int b  = zz;
  const int t0 = yy * 128;
  const int n0 = xx * 256;
  const int row0 = b * TT + t0;
  const bool hasK = (t0 < P);
  const bool hasQ = (t0 + 128 > P);
  __shared__ __align__(16) unsigned short Ah[128 * 40], Al[128 * 40];
  __shared__ __align__(16) unsigned short Bh[256 * 32], Bl[256 * 32];
  __shared__ float mus[128], rss[128];
  const int tid = threadIdx.x;
  if (tid < 128) {
    mus[tid] = stats[2 * (size_t)(row0 + tid)];
    rss[tid] = stats[2 * (size_t)(row0 + tid) + 1];
  }
  const int lane = tid & 63;
  const int wid  = tid >> 6;
  const int wm = (wid >> 2) * 64, wn = (wid & 3) * 64;
  const int lm = lane & 15, lq = lane >> 4;
  const int srow = lane >> 2, scol = (lane & 3) << 3;

  for (int pass = 0; pass < 2; pass++) {
    if (pass == 0 && !hasK) continue;
    if (pass == 1 && !hasQ) continue;
    const unsigned short* WThi = pass ? QH : KH;
    const unsigned short* WTlo = pass ? QL : KL;
    f4v acc[4][4];
#pragma unroll
    for (int i = 0; i < 4; i++)
#pragma unroll
      for (int j = 0; j < 4; j++) acc[i][j] = (f4v){0.f, 0.f, 0.f, 0.f};

    for (int kt = 0; kt < D_MODEL; kt += 32) {
      __syncthreads();
#pragma unroll
      for (int s = 0; s < 2; s++) {
        int seg = wid * 2 + s;
        int brow = n0 + seg * 16 + srow;
        gll16(&Bh[seg * 512], &WThi[(size_t)brow * 1024 + kt + scol]);
        gll16(&Bl[seg * 512], &WTlo[(size_t)brow * 1024 + kt + scol]);
      }
      {
        int m = tid >> 2, k8 = (tid & 3) << 3;
        const float* src = &X[(size_t)(row0 + m) * D_MODEL + kt + k8];
        float mu = mus[m], rs = rss[m];
        u16x8 hv, lv;
#pragma unroll
        for (int i = 0; i < 8; i++) {
          float nv = (src[i] - mu) * rs * lng[kt + k8 + i] + lnb[kt + k8 + i];
          unsigned short h, l;
          split_bf16(nv, h, l);
          hv[i] = h; lv[i] = l;
        }
        *(u16x8*)&Ah[m * 40 + k8] = hv;
        *(u16x8*)&Al[m * 40 + k8] = lv;
      }
      __syncthreads();
      s8v ah[4], al[4], bh[4], bl[4];
#pragma unroll
      for (int i = 0; i < 4; i++) {
        int ar = (wm + i * 16 + lm) * 40 + lq * 8;
        int br = (wn + i * 16 + lm) * 32 + lq * 8;
        ah[i] = *(const s8v*)&Ah[ar];
        al[i] = *(const s8v*)&Al[ar];
        bh[i] = *(const s8v*)&Bh[br];
        bl[i] = *(const s8v*)&Bl[br];
      }
#pragma unroll
      for (int mi = 0; mi < 4; mi++)
#pragma unroll
        for (int ni = 0; ni < 4; ni++) {
          acc[mi][ni] = __builtin_amdgcn_mfma_f32_16x16x32_bf16(ah[mi], bh[ni], acc[mi][ni], 0, 0, 0);
          acc[mi][ni] = __builtin_amdgcn_mfma_f32_16x16x32_bf16(ah[mi], bl[ni], acc[mi][ni], 0, 0, 0);
          acc[mi][ni] = __builtin_amdgcn_mfma_f32_16x16x32_bf16(al[mi], bh[ni], acc[mi][ni], 0, 0, 0);
        }
    }
#pragma unroll
    for (int mi = 0; mi < 4; mi++) {
#pragma unroll
      for (int r = 0; r < 4; r++) {
        int t = t0 + wm + mi * 16 + lq * 4 + r;
        bool ok = pass ? (t >= P) : (t < P);
        if (!ok) continue;
#pragma unroll
        for (int ni = 0; ni < 4; ni++)
          Y[((size_t)b * TT + t) * 512 + n0 + wn + ni * 16 + lm] = acc[mi][ni][r];
      }
    }
  }
}

// ------------- G, M, C_v Gram reductions via MFMA (partials, no atomics) -------------
__global__ __launch_bounds__(256) void build_gmc_mfma_k(
    const float* __restrict__ Y1, const float* __restrict__ Y2,
    const int* __restrict__ pref,
    float* __restrict__ Gp, float* __restrict__ Mp, float* __restrict__ Cp) {
  int P = pref[0]; P = P < 1 ? 1 : (P > TT - 1 ? TT - 1 : P);
  const int c  = blockIdx.x;
  const int bh = blockIdx.y;
  const int b = bh >> 4, h = bh & 15;
  const int chunk = (P + TCH - 1) / TCH;
  const int tb = c * chunk;
  const int te = min(tb + chunk, P);

  __shared__ __align__(16) unsigned short kCh[32 * 136], kCl[32 * 136];
  __shared__ __align__(16) unsigned short kPh[32 * 136], kPl[32 * 136];
  __shared__ __align__(16) unsigned short vTh[64 * 136], vTl[64 * 136];

  const int tid = threadIdx.x;
  const int wid = tid >> 6, lane = tid & 63;
  const int lm = lane & 15, lq = lane >> 4;

  f4v acc[4];
#pragma unroll
  for (int i = 0; i < 4; i++) acc[i] = (f4v){0.f, 0.f, 0.f, 0.f};

  for (int t0 = tb; t0 < te; t0 += 128) {
    const int len = (te - t0 < 128) ? (te - t0) : 128;
    __syncthreads();
    // stage keys: rows 0..128 map t = t0-1+row; kC[u=row-1] current, kP[u=row] prev
    for (int e = tid; e < 129 * 8; e += 256) {
      int row = e >> 3, j4 = (e & 7) << 2;
      int t = t0 - 1 + row;
      float4 kv = make_float4(0.f, 0.f, 0.f, 0.f);
      if (row <= len && t >= 0)
        kv = *(const float4*)&Y1[((size_t)b * TT + t) * 512 + h * 32 + j4];
      unsigned short hh[4], ll[4];
      split_bf16(kv.x, hh[0], ll[0]); split_bf16(kv.y, hh[1], ll[1]);
      split_bf16(kv.z, hh[2], ll[2]); split_bf16(kv.w, hh[3], ll[3]);
      if (row >= 1) {
#pragma unroll
        for (int q = 0; q < 4; q++) {
          kCh[(j4 + q) * 136 + row - 1] = hh[q];
          kCl[(j4 + q) * 136 + row - 1] = ll[q];
        }
      }
      if (row < 128) {
#pragma unroll
        for (int q = 0; q < 4; q++) {
          kPh[(j4 + q) * 136 + row] = hh[q];
          kPl[(j4 + q) * 136 + row] = ll[q];
        }
      }
    }
    // stage values: v_t[d] at u = row
    for (int e = tid; e < 128 * 16; e += 256) {
      int row = e >> 4, dj = (e & 15) << 2;
      int t = t0 + row;
      float4 vv = make_float4(0.f, 0.f, 0.f, 0.f);
      if (row < len)
        vv = *(const float4*)&Y2[((size_t)b * P + t) * 1024 + h * 64 + dj];
      unsigned short hh[4], ll[4];
      split_bf16(vv.x, hh[0], ll[0]); split_bf16(vv.y, hh[1], ll[1]);
      split_bf16(vv.z, hh[2], ll[2]); split_bf16(vv.w, hh[3], ll[3]);
#pragma unroll
      for (int q = 0; q < 4; q++) {
        vTh[(dj + q) * 136 + row] = hh[q];
        vTl[(dj + q) * 136 + row] = ll[q];
      }
    }
    __syncthreads();

#pragma unroll
    for (int kk = 0; kk < 128; kk += 32) {
      const int off = kk + lq * 8;
      if (wid == 0) {
        s8v h0 = *(const s8v*)&kCh[(0 + lm) * 136 + off];
        s8v h1 = *(const s8v*)&kCh[(16 + lm) * 136 + off];
        s8v l0 = *(const s8v*)&kCl[(0 + lm) * 136 + off];
        s8v l1 = *(const s8v*)&kCl[(16 + lm) * 136 + off];
        acc[0] = __builtin_amdgcn_mfma_f32_16x16x32_bf16(h0, h0, acc[0], 0, 0, 0);
        acc[0] = __builtin_amdgcn_mfma_f32_16x16x32_bf16(h0, l0, acc[0], 0, 0, 0);
        acc[0] = __builtin_amdgcn_mfma_f32_16x16x32_bf16(l0, h0, acc[0], 0, 0, 0);
        acc[1] = __builtin_amdgcn_mfma_f32_16x16x32_bf16(h0, h1, acc[1], 0, 0, 0);
        acc[1] = __builtin_amdgcn_mfma_f32_16x16x32_bf16(h0, l1, acc[1], 0, 0, 0);
        acc[1] = __builtin_amdgcn_mfma_f32_16x16x32_bf16(l0, h1, acc[1], 0, 0, 0);
        acc[2] = __builtin_amdgcn_mfma_f32_16x16x32_bf16(h1, h0, acc[2], 0, 0, 0);
        acc[2] = __builtin_amdgcn_mfma_f32_16x16x32_bf16(h1, l0, acc[2], 0, 0, 0);
        acc[2] = __builtin_amdgcn_mfma_f32_16x16x32_bf16(l1, h0, acc[2], 0, 0, 0);
        acc[3] = __builtin_amdgcn_mfma_f32_16x16x32_bf16(h1, h1, acc[3], 0, 0, 0);
        acc[3] = __builtin_amdgcn_mfma_f32_16x16x32_bf16(h1, l1, acc[3], 0, 0, 0);
        acc[3] = __builtin_amdgcn_mfma_f32_16x16x32_bf16(l1, h1, acc[3], 0, 0, 0);
      } else if (wid == 1) {
        s8v ah0 = *(const s8v*)&kCh[(0 + lm) * 136 + off];
        s8v ah1 = *(const s8v*)&kCh[(16 + lm) * 136 + off];
        s8v al0 = *(const s8v*)&kCl[(0 + lm) * 136 + off];
        s8v al1 = *(const s8v*)&kCl[(16 + lm) * 136 + off];
        s8v bh0 = *(const s8v*)&kPh[(0 + lm) * 136 + off];
        s8v bh1 = *(const s8v*)&kPh[(16 + lm) * 136 + off];
        s8v bl0 = *(const s8v*)&kPl[(0 + lm) * 136 + off];
        s8v bl1 = *(const s8v*)&kPl[(16 + lm) * 136 + off];
        acc[0] = __builtin_amdgcn_mfma_f32_16x16x32_bf16(ah0, bh0, acc[0], 0, 0, 0);
        acc[0] = __builtin_amdgcn_mfma_f32_16x16x32_bf16(ah0, bl0, acc[0], 0, 0, 0);
        acc[0] = __builtin_amdgcn_mfma_f32_16x16x32_bf16(al0, bh0, acc[0], 0, 0, 0);
        acc[1] = __builtin_amdgcn_mfma_f32_16x16x32_bf16(ah0, bh1, acc[1], 0, 0, 0);
        acc[1] = __builtin_amdgcn_mfma_f32_16x16x32_bf16(ah0, bl1, acc[1], 0, 0, 0);
        acc[1] = __builtin_amdgcn_mfma_f32_16x16x32_bf16(al0, bh1, acc[1], 0, 0, 0);
        acc[2] = __builtin_amdgcn_mfma_f32_16x16x32_bf16(ah1, bh0, acc[2], 0, 0, 0);
        acc[2] = __builtin_amdgcn_mfma_f32_16x16x32_bf16(ah1, bl0, acc[2], 0, 0, 0);
        acc[2] = __builtin_amdgcn_mfma_f32_16x16x32_bf16(al1, bh0, acc[2], 0, 0, 0);
        acc[3] = __builtin_amdgcn_mfma_f32_16x16x32_bf16(ah1, bh1, acc[3], 0, 0, 0);
        acc[3] = __builtin_amdgcn_mfma_f32_16x16x32_bf16(ah1, bl1, acc[3], 0, 0, 0);
        acc[3] = __builtin_amdgcn_mfma_f32_16x16x32_bf16(al1, bh1, acc[3], 0, 0, 0);
      } else {
        const int d0 = (wid - 2) * 32;
        s8v vh0 = *(const s8v*)&vTh[(d0 + lm) * 136 + off];
        s8v vh1 = *(const s8v*)&vTh[(d0 + 16 + lm) * 136 + off];
        s8v vl0 = *(const s8v*)&vTl[(d0 + lm) * 136 + off];
        s8v vl1 = *(const s8v*)&vTl[(d0 + 16 + lm) * 136 + off];
        s8v kh0 = *(const s8v*)&kCh[(0 + lm) * 136 + off];
        s8v kh1 = *(const s8v*)&kCh[(16 + lm) * 136 + off];
        s8v kl0 = *(const s8v*)&kCl[(0 + lm) * 136 + off];
        s8v kl1 = *(const s8v*)&kCl[(16 + lm) * 136 + off];
        acc[0] = __builtin_amdgcn_mfma_f32_16x16x32_bf16(vh0, kh0, acc[0], 0, 0, 0);
        acc[0] = __builtin_amdgcn_mfma_f32_16x16x32_bf16(vh0, kl0, acc[0], 0, 0, 0);
        acc[0] = __builtin_amdgcn_mfma_f32_16x16x32_bf16(vl0, kh0, acc[0], 0, 0, 0);
        acc[1] = __builtin_amdgcn_mfma_f32_16x16x32_bf16(vh0, kh1, acc[1], 0, 0, 0);
        acc[1] = __builtin_amdgcn_mfma_f32_16x16x32_bf16(vh0, kl1, acc[1], 0, 0, 0);
        acc[1] = __builtin_amdgcn_mfma_f32_16x16x32_bf16(vl0, kh1, acc[1], 0, 0, 0);
        acc[2] = __builtin_amdgcn_mfma_f32_16x16x32_bf16(vh1, kh0, acc[2], 0, 0, 0);
        acc[2] = __builtin_amdgcn_mfma_f32_16x16x32_bf16(vh1, kl0, acc[2], 0, 0, 0);
        acc[2] = __builtin_amdgcn_mfma_f32_16x16x32_bf16(vl1, kh0, acc[2], 0, 0, 0);
        acc[3] = __builtin_amdgcn_mfma_f32_16x16x32_bf16(vh1, kh1, acc[3], 0, 0, 0);
        acc[3] = __builtin_amdgcn_mfma_f32_16x16x32_bf16(vh1, kl1, acc[3], 0, 0, 0);
        acc[3] = __builtin_amdgcn_mfma_f32_16x16x32_bf16(vl1, kh1, acc[3], 0, 0, 0);
      }
    }
  }

  // write partials (D layout: col = lm, row = lq*4 + r)
  if (wid < 2) {
    float* dst = (wid == 0 ? Gp : Mp) + (size_t)(c * 64 + bh) * 1024;
#pragma unroll
    for (int t = 0; t < 4; t++) {
      int i0 = (t >> 1) * 16, j0 = (t & 1) * 16;
#pragma unroll
      for (int r = 0; r < 4; r++)
        dst[(i0 + lq * 4 + r) * 32 + j0 + lm] = acc[t][r];
    }
  } else {
    float* dst = Cp + (size_t)(c * 64 + bh) * 2048;
#pragma unroll
    for (int t = 0; t < 4; t++) {
      int d0 = (wid - 2) * 32 + (t >> 1) * 16, j0 = (t & 1) * 16;
#pragma unroll
      for (int r = 0; r < 4; r++)
        dst[(d0 + lq * 4 + r) * 32 + j0 + lm] = acc[t][r];
    }
  }
}

// ------- per-(b,h) operator: chol, G^{-1}, A_w, sigma, F = Cv*Gi*(s*M*Gi)^4 -------
// Tri-solves are register-resident (lane = column, fully unrolled -> no LDS
// write->read turnaround on the serial chain); Gi and L^{-1}M solves run
// CONCURRENTLY on wave0/wave1. Arithmetic order identical to block version.
__global__ __launch_bounds__(256) void solve_op_k(
    const float* __restrict__ Gp, const float* __restrict__ Mp,
    const float* __restrict__ Cp, const float* __restrict__ lridge,
    const float* __restrict__ lgamma, float* __restrict__ Ft) {
  __shared__ float Gs[32 * 33];
  __shared__ float Ms[32 * 32];
  __shared__ float Gi[32 * 32];
  __shared__ float W2s[32 * 33];
  __shared__ float Aw[32 * 33];
  __shared__ float Nn[32 * 32];
  __shared__ float N2[32 * 32];
  __shared__ float T1[32 * 32];
  __shared__ float Cs[64 * 32];
  __shared__ float red[256];
  const int bh = blockIdx.x;
  const int tid = threadIdx.x;
  const float ridge = expf(lridge[0]);

  for (int e = tid; e < 1024; e += 256) {
    int i = e >> 5, j = e & 31;
    float g = 0.f, m = 0.f;
#pragma unroll
    for (int cc = 0; cc < TCH; cc++) {
      g += Gp[(size_t)(cc * 64 + bh) * 1024 + e];
      m += Mp[(size_t)(cc * 64 + bh) * 1024 + e];
    }
    if (i == j) g += ridge;
    Gs[i * 33 + j] = g;
    Ms[e] = m;
  }
  for (int e = tid; e < 2048; e += 256) {
    float s = 0.f;
#pragma unroll
    for (int cc = 0; cc < TCH; cc++) s += Cp[(size_t)(cc * 64 + bh) * 2048 + e];
    Cs[e] = s;
  }
  __syncthreads();

  for (int j = 0; j < 32; j++) {
    float d = Gs[j * 33 + j];
    __syncthreads();
    float inv = 1.0f / sqrtf(d);
    if (tid >= j && tid < 32) Gs[tid * 33 + j] *= inv;
    __syncthreads();
    int w = 31 - j;
    for (int e = tid; e < w * w; e += 256) {
      int i = j + 1 + e / w, k = j + 1 + e % w;
      Gs[i * 33 + k] -= Gs[i * 33 + j] * Gs[k * 33 + j];
    }
    __syncthreads();
  }

  // wave0: Gi = G^{-1} (fwd+back on e_c); wave1: W2 = L^{-1} M (fwd). Concurrent.
  if (tid < 32) {
    const int c = tid;
    float w[32];
#pragma unroll
    for (int i = 0; i < 32; i++) {
      float s = (i == c) ? 1.0f : 0.0f;
#pragma unroll
      for (int j = 0; j < 32; j++)
        if (j < i) s -= Gs[i * 33 + j] * w[j];
      w[i] = s / Gs[i * 33 + i];
    }
#pragma unroll
    for (int i = 31; i >= 0; i--) {
      float s = w[i];
#pragma unroll
      for (int j = 0; j < 32; j++)
        if (j > i) s -= Gs[j * 33 + i] * w[j];
      w[i] = s / Gs[i * 33 + i];
    }
#pragma unroll
    for (int i = 0; i < 32; i++) Gi[i * 32 + c] = w[i];
  } else if (tid >= 64 && tid < 96) {
    const int c = tid - 64;
    float w[32];
#pragma unroll
    for (int i = 0; i < 32; i++) {
      float s = Ms[i * 32 + c];
#pragma unroll
      for (int j = 0; j < 32; j++)
        if (j < i) s -= Gs[i * 33 + j] * w[j];
      w[i] = s / Gs[i * 33 + i];
    }
#pragma unroll
    for (int i = 0; i < 32; i++) W2s[i * 33 + c] = w[i];
  }
  __syncthreads();
  // Aw (holds A_w^T; only norms consumed): column c solves L a = (L^{-1}M) row c
  if (tid < 32) {
    const int c = tid;
    float a[32];
#pragma unroll
    for (int i = 0; i < 32; i++) {
      float s = W2s[c * 33 + i];
#pragma unroll
      for (int j = 0; j < 32; j++)
        if (j < i) s -= Gs[i * 33 + j] * a[j];
      a[i] = s / Gs[i * 33 + i];
    }
#pragma unroll
    for (int i = 0; i < 32; i++) Aw[i * 33 + c] = a[i];
  }
  __syncthreads();

  float s0 = 0.0f;
  for (int e = tid; e < 1024; e += 256) {
    float a = Aw[(e >> 5) * 33 + (e & 31)];
    s0 += a * a;
  }
  red[tid] = s0;
  __syncthreads();
  for (int off = 128; off > 0; off >>= 1) {
    if (tid < off) red[tid] += red[tid + off];
    __syncthreads();
  }
  float frob2 = red[0];
  float sigma;
  if (frob2 <= 1.0f) {
    sigma = sqrtf(frob2);
  } else {
    // in-wave power iteration, LDS reads (no register arrays -> no spill risk)
    if (tid < 32) {
      const int i = tid;
      float v = 1.0f + 0.001f * (float)i;
      float sig = 0.0f, prev = -1.0f;
      for (int it = 0; it < 64; it++) {
        float u = 0.0f;
#pragma unroll
        for (int j = 0; j < 32; j++) u += Aw[i * 33 + j] * __shfl(v, j, 64);
        float n2 = u * u;
#pragma unroll
        for (int o = 16; o > 0; o >>= 1) n2 += __shfl_xor(n2, o, 64);
        u /= fmaxf(sqrtf(n2), 1e-30f);
        float vn = 0.0f;
#pragma unroll
        for (int j = 0; j < 32; j++) vn += Aw[j * 33 + i] * __shfl(u, j, 64);
        float m2 = vn * vn;
#pragma unroll
        for (int o = 16; o > 0; o >>= 1) m2 += __shfl_xor(m2, o, 64);
        sig = sqrtf(m2);
        v = vn / fmaxf(sig, 1e-30f);
        if (it >= 7 && fabsf(sig - prev) <= 1e-7f * sig) break;
        prev = sig;
      }
      if (i == 0) red[0] = sig;
    }
    __syncthreads();
    sigma = red[0];
  }
  float gamma_c = fminf(expf(lgamma[0]), 1.0f);
  float scale = gamma_c / fmaxf(fmaxf(sigma, 1e-8f), 1.0f);

  for (int e = tid; e < 1024; e += 256) {
    int i = e >> 5, c = e & 31;
    float s = 0;
#pragma unroll
    for (int k = 0; k < 32; k++) s += Ms[i * 32 + k] * Gi[k * 32 + c];
    Nn[e] = scale * s;
  }
  __syncthreads();
  for (int e = tid; e < 1024; e += 256) {
    int i = e >> 5, c = e & 31;
    float s = 0;
#pragma unroll
    for (int k = 0; k < 32; k++) s += Nn[i * 32 + k] * Nn[k * 32 + c];
    N2[e] = s;
  }
  __syncthreads();
  for (int e = tid; e < 1024; e += 256) {
    int i = e >> 5, c = e & 31;
    float s = 0;
#pragma unroll
    for (int k = 0; k < 32; k++) s += N2[i * 32 + k] * N2[k * 32 + c];
    Ms[e] = s;
  }
  __syncthreads();
  for (int e = tid; e < 1024; e += 256) {
    int i = e >> 5, c = e & 31;
    float s = 0;
#pragma unroll
    for (int k = 0; k < 32; k++) s += Gi[i * 32 + k] * Ms[k * 32 + c];
    T1[e] = s;
  }
  __syncthreads();
  for (int e = tid; e < 2048; e += 256) {
    int j = e >> 6, d = e & 63;
    float s = 0;
#pragma unroll
    for (int k = 0; k < 32; k++) s += Cs[d * 32 + k] * T1[k * 32 + j];
    Ft[(size_t)bh * 2048 + e] = s;
  }
}

// ------------- apply F^T per (head, 128-token chunk) -> full_hi (bf16) -------------
// FH written chunk-swizzled within each head's 64-col group (gemm_out consumes).
__global__ __launch_bounds__(256) void apply_k(const float* __restrict__ Y1,
                                               const float* __restrict__ Ft,
                                               unsigned short* __restrict__ FH) {
  __shared__ float xs[128 * 32];
  const int h = blockIdx.y;
  const int r0 = blockIdx.x * 128;
  const int bh = (r0 >> 12) * NH + h;
  const int tid = threadIdx.x;
  const int d = tid & 63, t0 = tid >> 6;
  float fcol[32];
  const float* fb = &Ft[(size_t)bh * 2048 + d];
#pragma unroll
  for (int j = 0; j < 32; j++) fcol[j] = fb[j * 64];
  for (int e = tid; e < 1024; e += 256) {
    int row = e >> 3, j4 = (e & 7) << 2;
    *(float4*)&xs[row * 32 + j4] =
        *(const float4*)&Y1[((size_t)(r0 + row)) * 512 + h * 32 + j4];
  }
  __syncthreads();
  const int dq = d >> 3, dr = d & 7;
  for (int tl = t0; tl < 128; tl += 4) {
    float s = 0;
#pragma unroll
    for (int j = 0; j < 32; j++) s += xs[tl * 32 + j] * fcol[j];
    int col = h * 64 + ((dq ^ (tl & 7)) << 3) + dr;
    FH[((size_t)(r0 + tl)) * 1024 + col] = bf16_rne(s);
  }
}

// ------------- output GEMM (MFMA): out = sg * full @ Wo ; A=hi, B=hi+lo -------------
// 256x128 tile, BK=64, 8 waves, double-buffered LDS, counted vmcnt (never 0 in
// steady state), pre-swizzled-global + swizzled ds_read (bank-floor reads).
__global__ __launch_bounds__(512) void gemm_out_k(
    const unsigned short* __restrict__ FH,
    const unsigned short* __restrict__ WThi, const unsigned short* __restrict__ WTlo,
    const float* __restrict__ alpha, float* __restrict__ out) {
  __shared__ __align__(16) unsigned short lds[65536];  // 128 KB: A 2x32K, Bh 2x16K, Bl 2x16K
  int xx, yy, zz;
  xcd_swz(8, 64, xx, yy, zz);
  const int m0 = yy * 256;
  const int n0 = xx * 128;
  const int tid = threadIdx.x;
  const int lane = tid & 63;
  const int wid  = tid >> 6;                 // 0..7
  const int wm = (wid >> 1) * 64;            // 4 M-waves x 64 rows
  const int wn = (wid & 1) * 64;             // 2 N-waves x 64 cols
  const int lm = lane & 15, lq = lane >> 4;
  const int l8 = lane >> 3, c8 = (lane & 7) << 3;  // staging: 8 rows x 8 chunks per issue

  f4v acc[4][4];
#pragma unroll
  for (int i = 0; i < 4; i++)
#pragma unroll
    for (int j = 0; j < 4; j++) acc[i][j] = (f4v){0.f, 0.f, 0.f, 0.f};

  auto STAGE = [&](int t, int buf) {
    const int kt = t * 64;
#pragma unroll
    for (int i = 0; i < 4; i++) {            // A: 4 issues/wave (32 total)
      int iss = wid * 4 + i;
      gll16(&lds[buf * 16384 + iss * 512],
            &FH[(size_t)(m0 + iss * 8 + l8) * 1024 + kt + c8]);
    }
#pragma unroll
    for (int i = 0; i < 2; i++) {            // Bh: 2 issues/wave (16 total)
      int iss = wid * 2 + i;
      gll16(&lds[32768 + buf * 8192 + iss * 512],
            &WThi[(size_t)(n0 + iss * 8 + l8) * 1024 + kt + c8]);
    }
#pragma unroll
    for (int i = 0; i < 2; i++) {            // Bl
      int iss = wid * 2 + i;
      gll16(&lds[49152 + buf * 8192 + iss * 512],
            &WTlo[(size_t)(n0 + iss * 8 + l8) * 1024 + kt + c8]);
    }
  };

  STAGE(0, 0);
  STAGE(1, 1);

  for (int t = 0; t < 16; t++) {
    const int buf = t & 1;
    if (t < 15) asm volatile("s_waitcnt vmcnt(8)" ::: "memory");
    else        asm volatile("s_waitcnt vmcnt(0)" ::: "memory");
    __builtin_amdgcn_s_barrier();
    const unsigned short* Ab  = &lds[buf * 16384];
    const unsigned short* Bhb = &lds[32768 + buf * 8192];
    const unsigned short* Blb = &lds[49152 + buf * 8192];
    __builtin_amdgcn_s_setprio(1);
#pragma unroll
    for (int kk = 0; kk < 2; kk++) {
      s8v ah[4], bh[4], bl[4];
#pragma unroll
      for (int i = 0; i < 4; i++) {
        int rA = wm + i * 16 + lm;
        int rB = wn + i * 16 + lm;
        int sA = (((kk * 4 + lq) ^ (rA & 7)) << 3);
        int sB = (((kk * 4 + lq) ^ (rB & 7)) << 3);
        ah[i] = *(const s8v*)&Ab[rA * 64 + sA];
        bh[i] = *(const s8v*)&Bhb[rB * 64 + sB];
        bl[i] = *(const s8v*)&Blb[rB * 64 + sB];
      }
#pragma unroll
      for (int mi = 0; mi < 4; mi++)
#pragma unroll
        for (int ni = 0; ni < 4; ni++) {
          acc[mi][ni] = __builtin_amdgcn_mfma_f32_16x16x32_bf16(ah[mi], bh[ni], acc[mi][ni], 0, 0, 0);
          acc[mi][ni] = __builtin_amdgcn_mfma_f32_16x16x32_bf16(ah[mi], bl[ni], acc[mi][ni], 0, 0, 0);
        }
    }
    __builtin_amdgcn_s_setprio(0);
    __builtin_amdgcn_sched_barrier(0);
    __builtin_amdgcn_s_barrier();
    if (t < 14) STAGE(t + 2, buf);
  }

  float sg = 1.0f / (1.0f + expf(-alpha[0]));
#pragma unroll
  for (int mi = 0; mi < 4; mi++)
#pragma unroll
    for (int r = 0; r < 4; r++) {
      size_t orow = (size_t)(m0 + wm + mi * 16 + lq * 4 + r);
#pragma unroll
      for (int ni = 0; ni < 4; ni++)
        out[orow * 1024 + n0 + wn + ni * 16 + lm] = sg * acc[mi][ni][r];
    }
}

extern "C" void kernel_launch(void* const* d_in, const int* in_sizes, int n_in,
                              void* d_out, int out_size, void* d_ws, size_t ws_size,
                              hipStream_t stream) {
  const float* X      = (const float*)d_in[0];
  const float* Wk     = (const float*)d_in[1];
  const float* Wq     = (const float*)d_in[2];
  const float* Wv     = (const float*)d_in[3];
  const float* Wo     = (const float*)d_in[4];
  const float* lng    = (const float*)d_in[5];
  const float* lnb    = (const float*)d_in[6];
  const float* alpha  = (const float*)d_in[7];
  const float* lridge = (const float*)d_in[8];
  const float* lgamma = (const float*)d_in[9];
  const int*   pref   = (const int*)d_in[10];
  float* out = (float*)d_out;
  char* ws = (char*)d_ws;
  float* stats = (float*)(ws + OFF_STATS);
  float* Gp    = (float*)(ws + OFF_GP);
  float* Mp    = (float*)(ws + OFF_MP);
  float* Cp    = (float*)(ws + OFF_CP);
  float* Ft    = (float*)(ws + OFF_FT);
  unsigned short* WKH = (unsigned short*)(ws + OFF_WKH);
  unsigned short* WKL = (unsigned short*)(ws + OFF_WKL);
  unsigned short* WQH = (unsigned short*)(ws + OFF_WQH);
  unsigned short* WQL = (unsigned short*)(ws + OFF_WQL);
  unsigned short* WVH = (unsigned short*)(ws + OFF_WVH);
  unsigned short* WVL = (unsigned short*)(ws + OFF_WVL);
  unsigned short* WOH = (unsigned short*)(ws + OFF_WOH);
  unsigned short* WOL = (unsigned short*)(ws + OFF_WOL);
  float* Y1 = (float*)(ws + OFF_Y1);
  float* Y2 = (float*)(ws + OFF_Y2);
  unsigned short* FH = (unsigned short*)(ws + OFF_FH);

  ln_stats_k<<<16384, 256, 0, stream>>>(X, stats);
  prep_w_k<<<dim3(16, 32), 256, 0, stream>>>(Wk, 512, WKH, WKL, 0);
  prep_w_k<<<dim3(16, 32), 256, 0, stream>>>(Wq, 512, WQH, WQL, 0);
  prep_w_k<<<dim3(32, 32), 256, 0, stream>>>(Wv, 1024, WVH, WVL, 0);
  prep_w_k<<<dim3(32, 32), 256, 0, stream>>>(Wo, 1024, WOH, WOL, 1);
  gemm_kq_k<<<dim3(2, 32, NB), 512, 0, stream>>>(X, stats, lng, lnb, WKH, WKL, WQH, WQL, pref, Y1);
  gemm_proj_k<<<dim3(4, 32, NB), 512, 0, stream>>>(X, stats, lng, lnb, WVH, WVL, 1024, pref, 2, Y2);
  build_gmc_mfma_k<<<dim3(TCH, 64), 256, 0, stream>>>(Y1, Y2, pref, Gp, Mp, Cp);
  solve_op_k<<<64, 256, 0, stream>>>(Gp, Mp, Cp, lridge, lgamma, Ft);
  apply_k<<<dim3(128, NH), 256, 0, stream>>>(Y1, Ft, FH);
  gemm_out_k<<<dim3(8, 64), 512, 0, stream>>>(FH, WOH, WOL, alpha, out);
}

// Round 8
// 418.911 us; speedup vs baseline: 1.1320x; 1.0450x over previous
//
#include <hip/hip_runtime.h>
#include <math.h>

#define D_MODEL 1024
#define TT 4096
#define NB 4
#define NH 16
#define TCH 8

typedef __attribute__((ext_vector_type(8))) short s8v;
typedef __attribute__((ext_vector_type(4))) float f4v;
typedef __attribute__((ext_vector_type(8))) unsigned short u16x8;

// ---- workspace layout (bytes); peak ~88 MB (proven budget 100 MB) ----
#define OFF_STATS ((size_t)0)
#define OFF_GP    ((size_t)(1) << 20)    // 8*64*1024*4 = 2 MB partials
#define OFF_MP    ((size_t)(3) << 20)    // 2 MB
#define OFF_CP    ((size_t)(5) << 20)    // 8*64*2048*4 = 4 MB
#define OFF_FT    ((size_t)(9) << 20)    // 512 KB
#define OFF_WKH   ((size_t)(10) << 20)
#define OFF_WKL   ((size_t)(11) << 20)
#define OFF_WQH   ((size_t)(12) << 20)
#define OFF_WQL   ((size_t)(13) << 20)
#define OFF_WVH   ((size_t)(14) << 20)
#define OFF_WVL   ((size_t)(16) << 20)
#define OFF_WOH   ((size_t)(18) << 20)
#define OFF_WOL   ((size_t)(20) << 20)
#define OFF_Y1    ((size_t)(22) << 20)   // 32 MB
#define OFF_Y2    ((size_t)(54) << 20)   // P*NB*1024*4; FH overlays after build_gmc
#define OFF_FH    OFF_Y2

__device__ __forceinline__ unsigned short bf16_rne(float x) {
  unsigned u = __float_as_uint(x);
  return (unsigned short)((u + 0x7fffu + ((u >> 16) & 1u)) >> 16);
}
__device__ __forceinline__ void split_bf16(float x, unsigned short& h, unsigned short& l) {
  unsigned u = __float_as_uint(x);
  unsigned r = (u + 0x7fffu + ((u >> 16) & 1u)) & 0xffff0000u;
  h = (unsigned short)(r >> 16);
  float res = x - __uint_as_float(r);
  l = bf16_rne(res);
}

// async global->LDS, 16 B per lane; lds base must be wave-uniform (HW adds lane*16)
__device__ __forceinline__ void gll16(unsigned short* lds, const unsigned short* g) {
  __builtin_amdgcn_global_load_lds(
      (__attribute__((address_space(1))) void*)(void*)(g),
      (__attribute__((address_space(3))) void*)(lds), 16, 0, 0);
}

// bijective XCD swizzle: the gx blocks sharing one (y,z) land consecutively on ONE
// XCD; (y,z) values strided by 8 across XCDs (keeps P-masked kernels balanced).
__device__ __forceinline__ void xcd_swz(int gx, int gy, int& x, int& y, int& z) {
  int wg = blockIdx.x + gx * (blockIdx.y + gy * blockIdx.z);
  int k = wg & 7, j = wg >> 3;
  x = j % gx;
  int yz = k + ((j / gx) << 3);
  y = yz % gy;
  z = yz / gy;
}

// ---------------- LayerNorm statistics: one block per row ----------------
__global__ __launch_bounds__(256) void ln_stats_k(const float* __restrict__ X,
                                                  float* __restrict__ stats) {
  int r = blockIdx.x;
  const float4 v = ((const float4*)(X + (size_t)r * D_MODEL))[threadIdx.x];
  float s  = v.x + v.y + v.z + v.w;
  float ss = v.x * v.x + v.y * v.y + v.z * v.z + v.w * v.w;
#pragma unroll
  for (int off = 32; off > 0; off >>= 1) {
    s  += __shfl_down(s, off, 64);
    ss += __shfl_down(ss, off, 64);
  }
  __shared__ float as_[4], bs_[4];
  int w = threadIdx.x >> 6, lane = threadIdx.x & 63;
  if (lane == 0) { as_[w] = s; bs_[w] = ss; }
  __syncthreads();
  if (threadIdx.x == 0) {
    float S  = as_[0] + as_[1] + as_[2] + as_[3];
    float SS = bs_[0] + bs_[1] + bs_[2] + bs_[3];
    float mu  = S * (1.0f / D_MODEL);
    float var = SS * (1.0f / D_MODEL) - mu * mu;
    stats[2 * (size_t)r]     = mu;
    stats[2 * (size_t)r + 1] = 1.0f / sqrtf(var + 1e-5f);
  }
}

// ------- prep: transpose W[K][N] -> WT_hi/lo [N][K] bf16 split -------
// swz=1: XOR 16B-chunk idx with row&7 within 64-col groups (gemm_out, BK=64).
// swz=2: XOR 16B-chunk idx with (row>>1)&3 within 32-col groups (gemm_ln, BK=32).
__global__ __launch_bounds__(256) void prep_w_k(const float* __restrict__ W, int N,
                                                unsigned short* __restrict__ Thi,
                                                unsigned short* __restrict__ Tlo,
                                                int swz) {
  __shared__ float tileT[32 * 33];
  const int n0 = blockIdx.x * 32, k0 = blockIdx.y * 32;
  const int tid = threadIdx.x;
  {
    int k_l = tid >> 3, n4 = (tid & 7) << 2;
    float4 v = *(const float4*)&W[(size_t)(k0 + k_l) * N + n0 + n4];
    tileT[(n4 + 0) * 33 + k_l] = v.x;
    tileT[(n4 + 1) * 33 + k_l] = v.y;
    tileT[(n4 + 2) * 33 + k_l] = v.z;
    tileT[(n4 + 3) * 33 + k_l] = v.w;
  }
  __syncthreads();
  {
    int n_l = tid >> 3, k4 = (tid & 7) << 2;
    unsigned short h[4], l[4];
#pragma unroll
    for (int i = 0; i < 4; i++) split_bf16(tileT[n_l * 33 + k4 + i], h[i], l[i]);
    int kc = k0 + k4;
    int col = kc;
    if (swz == 1)
      col = (kc & ~63) | ((((kc >> 3) & 7) ^ (n_l & 7)) << 3) | (kc & 7);
    else if (swz == 2)
      col = (kc & ~31) | ((((kc >> 3) & 3) ^ ((n_l >> 1) & 3)) << 3) | (kc & 7);
    *(ushort4*)&Thi[(size_t)(n0 + n_l) * 1024 + col] = make_ushort4(h[0], h[1], h[2], h[3]);
    *(ushort4*)&Tlo[(size_t)(n0 + n_l) * 1024 + col] = make_ushort4(l[0], l[1], l[2], l[3]);
  }
}

// ------- fused LN + projection GEMM, deep-pipelined (counted vmcnt) -------
// 128x256 tile, BK=32, 512 thr, 8 waves (2Mx4N, 64x64/wave). B hi/lo double-
// buffered via global_load_lds (pre-swizzled global, swizzled ds_read); A (LN+
// split) reg-pipelined one tile ahead (xE/xO static sets). 6 VMEM/wave/iter ->
// steady-state s_waitcnt vmcnt(6), never 0. MFMA order bit-identical to the
// 2-barrier version. mode 0: K/Q merged -> Y1; mode 2: V -> Y2 compact.
__global__ __launch_bounds__(512) void gemm_ln_k(
    const float* __restrict__ X, const float* __restrict__ stats,
    const float* __restrict__ lng, const float* __restrict__ lnb,
    const unsigned short* __restrict__ BH0, const unsigned short* __restrict__ BL0,
    const unsigned short* __restrict__ BH1, const unsigned short* __restrict__ BL1,
    const int* __restrict__ pref, int mode, int Nw, float* __restrict__ Y) {
  int P = pref[0]; P = P < 1 ? 1 : (P > TT - 1 ? TT - 1 : P);
  int xx, yy, zz;
  xcd_swz(gridDim.x, 32, xx, yy, zz);
  const int b  = zz;
  const int t0 = yy * 128;
  const int n0 = xx * 256;
  if (mode == 2 && t0 >= P) return;
  const int row0 = b * TT + t0;
  const bool hasK = (t0 < P);
  const bool hasQ = (t0 + 128 > P);

  __shared__ __align__(16) unsigned short aH[2 * 128 * 40], aL[2 * 128 * 40];
  __shared__ __align__(16) unsigned short bH[2 * 256 * 32], bL[2 * 256 * 32];
  __shared__ float lngs[1024], lnbs[1024];

  const int tid = threadIdx.x;
  const int lane = tid & 63;
  const int wid  = tid >> 6;
  const int wm = (wid >> 2) * 64, wn = (wid & 3) * 64;
  const int lm = lane & 15, lq = lane >> 4;
  const int arow = tid >> 2, acol = (tid & 3) << 3;   // A stage: 128 rows x 4 chunks
  const int l4 = lane >> 2, c4 = (lane & 3) << 3;     // B stage: 16 rows x 4 chunks

  for (int e = tid; e < 1024; e += 512) { lngs[e] = lng[e]; lnbs[e] = lnb[e]; }
  const float mu = stats[2 * (size_t)(row0 + arow)];
  const float rs = stats[2 * (size_t)(row0 + arow) + 1];

  for (int pass = 0; pass < 2; ++pass) {
    if (mode == 2) { if (pass == 1) break; }
    else { if (pass == 0 && !hasK) continue; if (pass == 1 && !hasQ) continue; }
    const unsigned short* WH = pass ? BH1 : BH0;
    const unsigned short* WL = pass ? BL1 : BL0;

    f4v acc[4][4];
#pragma unroll
    for (int i = 0; i < 4; i++)
#pragma unroll
      for (int j = 0; j < 4; j++) acc[i][j] = (f4v){0.f, 0.f, 0.f, 0.f};

    float4 xE[2], xO[2];

    auto XLOAD = [&](int t, float4 (&xr)[2]) {
      const float* src = &X[(size_t)(row0 + arow) * 1024 + t * 32 + acol];
      xr[0] = *(const float4*)src;
      xr[1] = *(const float4*)(src + 4);
    };
    auto STAGEB = [&](int t, int buf) {
      const int kt = t * 32;
#pragma unroll
      for (int i = 0; i < 2; i++) {
        int iss = wid * 2 + i;
        int r = n0 + iss * 16 + l4;
        gll16(&bH[buf * 8192 + iss * 512], &WH[(size_t)r * 1024 + kt + c4]);
        gll16(&bL[buf * 8192 + iss * 512], &WL[(size_t)r * 1024 + kt + c4]);
      }
    };
    auto LNW = [&](int tt, float4 (&xr)[2], int abuf) {
      const int kt = tt * 32;
      float4 lg0 = *(const float4*)&lngs[kt + acol];
      float4 lg1 = *(const float4*)&lngs[kt + acol + 4];
      float4 lb0 = *(const float4*)&lnbs[kt + acol];
      float4 lb1 = *(const float4*)&lnbs[kt + acol + 4];
      float xv[8] = {xr[0].x, xr[0].y, xr[0].z, xr[0].w,
                     xr[1].x, xr[1].y, xr[1].z, xr[1].w};
      float lgv[8] = {lg0.x, lg0.y, lg0.z, lg0.w, lg1.x, lg1.y, lg1.z, lg1.w};
      float lbv[8] = {lb0.x, lb0.y, lb0.z, lb0.w, lb1.x, lb1.y, lb1.z, lb1.w};
      u16x8 hv, lv;
#pragma unroll
      for (int i = 0; i < 8; i++) {
        float nv = (xv[i] - mu) * rs * lgv[i] + lbv[i];
        unsigned short h, l;
        split_bf16(nv, h, l);
        hv[i] = h; lv[i] = l;
      }
      int ao = abuf * 5120 + arow * 40 + acol;
      *(u16x8*)&aH[ao] = hv;
      *(u16x8*)&aL[ao] = lv;
    };

    auto ITER = [&](int t, float4 (&xrd)[2], float4 (&xwr)[2]) {
      const int buf = t & 1;
      asm volatile("s_waitcnt vmcnt(6)" ::: "memory");
      __builtin_amdgcn_s_barrier();
      s8v ah[4], al[4], bh[4], bl[4];
#pragma unroll
      for (int i = 0; i < 4; i++) {
        int rA = wm + i * 16 + lm;
        int rB = wn + i * 16 + lm;
        int ao = buf * 5120 + rA * 40 + lq * 8;
        int bo = buf * 8192 + rB * 32 + ((lq ^ ((rB >> 1) & 3)) << 3);
        ah[i] = *(const s8v*)&aH[ao];
        al[i] = *(const s8v*)&aL[ao];
        bh[i] = *(const s8v*)&bH[bo];
        bl[i] = *(const s8v*)&bL[bo];
      }
      __builtin_amdgcn_s_setprio(1);
#pragma unroll
      for (int mi = 0; mi < 4; mi++)
#pragma unroll
        for (int ni = 0; ni < 4; ni++) {
          acc[mi][ni] = __builtin_amdgcn_mfma_f32_16x16x32_bf16(ah[mi], bh[ni], acc[mi][ni], 0, 0, 0);
          acc[mi][ni] = __builtin_amdgcn_mfma_f32_16x16x32_bf16(ah[mi], bl[ni], acc[mi][ni], 0, 0, 0);
          acc[mi][ni] = __builtin_amdgcn_mfma_f32_16x16x32_bf16(al[mi], bh[ni], acc[mi][ni], 0, 0, 0);
        }
      __builtin_amdgcn_s_setprio(0);
      if (t < 31) LNW(t + 1, xrd, buf ^ 1);
      asm volatile("s_waitcnt lgkmcnt(0)" ::: "memory");
      __builtin_amdgcn_s_barrier();
      if (t < 30) {
        XLOAD(t + 2, xwr);
        STAGEB(t + 2, buf);
      }
    };

    // prologue
    XLOAD(0, xE); STAGEB(0, 0);
    XLOAD(1, xO); STAGEB(1, 1);
    __syncthreads();              // drain + publish lngs/lnbs
    LNW(0, xE, 0);
    __syncthreads();              // publish A(0)

    for (int t2 = 0; t2 < 32; t2 += 2) {
      ITER(t2,     xO, xE);       // even iter: LNW reads xO, XLOAD fills xE
      ITER(t2 + 1, xE, xO);
    }

#pragma unroll
    for (int mi = 0; mi < 4; mi++) {
#pragma unroll
      for (int r = 0; r < 4; r++) {
        int t = t0 + wm + mi * 16 + lq * 4 + r;
        bool ok = (mode == 2) ? (t < P) : (pass ? (t >= P) : (t < P));
        if (!ok) continue;
        size_t orow = (mode == 2) ? ((size_t)b * P + t) : ((size_t)b * TT + t);
#pragma unroll
        for (int ni = 0; ni < 4; ni++)
          Y[orow * Nw + n0 + wn + ni * 16 + lm] = acc[mi][ni][r];
      }
    }
  }
}

// ------------- G, M, C_v Gram reductions via MFMA (partials, no atomics) -------------
__global__ __launch_bounds__(256) void build_gmc_mfma_k(
    const float* __restrict__ Y1, const float* __restrict__ Y2,
    const int* __restrict__ pref,
    float* __restrict__ Gp, float* __restrict__ Mp, float* __restrict__ Cp) {
  int P = pref[0]; P = P < 1 ? 1 : (P > TT - 1 ? TT - 1 : P);
  const int c  = blockIdx.x;
  const int bh = blockIdx.y;
  const int b = bh >> 4, h = bh & 15;
  const int chunk = (P + TCH - 1) / TCH;
  const int tb = c * chunk;
  const int te = min(tb + chunk, P);

  __shared__ __align__(16) unsigned short kCh[32 * 136], kCl[32 * 136];
  __shared__ __align__(16) unsigned short kPh[32 * 136], kPl[32 * 136];
  __shared__ __align__(16) unsigned short vTh[64 * 136], vTl[64 * 136];

  const int tid = threadIdx.x;
  const int wid = tid >> 6, lane = tid & 63;
  const int lm = lane & 15, lq = lane >> 4;

  f4v acc[4];
#pragma unroll
  for (int i = 0; i < 4; i++) acc[i] = (f4v){0.f, 0.f, 0.f, 0.f};

  for (int t0 = tb; t0 < te; t0 += 128) {
    const int len = (te - t0 < 128) ? (te - t0) : 128;
    __syncthreads();
    // stage keys: rows 0..128 map t = t0-1+row; kC[u=row-1] current, kP[u=row] prev
    for (int e = tid; e < 129 * 8; e += 256) {
      int row = e >> 3, j4 = (e & 7) << 2;
      int t = t0 - 1 + row;
      float4 kv = make_float4(0.f, 0.f, 0.f, 0.f);
      if (row <= len && t >= 0)
        kv = *(const float4*)&Y1[((size_t)b * TT + t) * 512 + h * 32 + j4];
      unsigned short hh[4], ll[4];
      split_bf16(kv.x, hh[0], ll[0]); split_bf16(kv.y, hh[1], ll[1]);
      split_bf16(kv.z, hh[2], ll[2]); split_bf16(kv.w, hh[3], ll[3]);
      if (row >= 1) {
#pragma unroll
        for (int q = 0; q < 4; q++) {
          kCh[(j4 + q) * 136 + row - 1] = hh[q];
          kCl[(j4 + q) * 136 + row - 1] = ll[q];
        }
      }
      if (row < 128) {
#pragma unroll
        for (int q = 0; q < 4; q++) {
          kPh[(j4 + q) * 136 + row] = hh[q];
          kPl[(j4 + q) * 136 + row] = ll[q];
        }
      }
    }
    // stage values: v_t[d] at u = row
    for (int e = tid; e < 128 * 16; e += 256) {
      int row = e >> 4, dj = (e & 15) << 2;
      int t = t0 + row;
      float4 vv = make_float4(0.f, 0.f, 0.f, 0.f);
      if (row < len)
        vv = *(const float4*)&Y2[((size_t)b * P + t) * 1024 + h * 64 + dj];
      unsigned short hh[4], ll[4];
      split_bf16(vv.x, hh[0], ll[0]); split_bf16(vv.y, hh[1], ll[1]);
      split_bf16(vv.z, hh[2], ll[2]); split_bf16(vv.w, hh[3], ll[3]);
#pragma unroll
      for (int q = 0; q < 4; q++) {
        vTh[(dj + q) * 136 + row] = hh[q];
        vTl[(dj + q) * 136 + row] = ll[q];
      }
    }
    __syncthreads();

#pragma unroll
    for (int kk = 0; kk < 128; kk += 32) {
      const int off = kk + lq * 8;
      if (wid == 0) {
        s8v h0 = *(const s8v*)&kCh[(0 + lm) * 136 + off];
        s8v h1 = *(const s8v*)&kCh[(16 + lm) * 136 + off];
        s8v l0 = *(const s8v*)&kCl[(0 + lm) * 136 + off];
        s8v l1 = *(const s8v*)&kCl[(16 + lm) * 136 + off];
        acc[0] = __builtin_amdgcn_mfma_f32_16x16x32_bf16(h0, h0, acc[0], 0, 0, 0);
        acc[0] = __builtin_amdgcn_mfma_f32_16x16x32_bf16(h0, l0, acc[0], 0, 0, 0);
        acc[0] = __builtin_amdgcn_mfma_f32_16x16x32_bf16(l0, h0, acc[0], 0, 0, 0);
        acc[1] = __builtin_amdgcn_mfma_f32_16x16x32_bf16(h0, h1, acc[1], 0, 0, 0);
        acc[1] = __builtin_amdgcn_mfma_f32_16x16x32_bf16(h0, l1, acc[1], 0, 0, 0);
        acc[1] = __builtin_amdgcn_mfma_f32_16x16x32_bf16(l0, h1, acc[1], 0, 0, 0);
        acc[2] = __builtin_amdgcn_mfma_f32_16x16x32_bf16(h1, h0, acc[2], 0, 0, 0);
        acc[2] = __builtin_amdgcn_mfma_f32_16x16x32_bf16(h1, l0, acc[2], 0, 0, 0);
        acc[2] = __builtin_amdgcn_mfma_f32_16x16x32_bf16(l1, h0, acc[2], 0, 0, 0);
        acc[3] = __builtin_amdgcn_mfma_f32_16x16x32_bf16(h1, h1, acc[3], 0, 0, 0);
        acc[3] = __builtin_amdgcn_mfma_f32_16x16x32_bf16(h1, l1, acc[3], 0, 0, 0);
        acc[3] = __builtin_amdgcn_mfma_f32_16x16x32_bf16(l1, h1, acc[3], 0, 0, 0);
      } else if (wid == 1) {
        s8v ah0 = *(const s8v*)&kCh[(0 + lm) * 136 + off];
        s8v ah1 = *(const s8v*)&kCh[(16 + lm) * 136 + off];
        s8v al0 = *(const s8v*)&kCl[(0 + lm) * 136 + off];
        s8v al1 = *(const s8v*)&kCl[(16 + lm) * 136 + off];
        s8v bh0 = *(const s8v*)&kPh[(0 + lm) * 136 + off];
        s8v bh1 = *(const s8v*)&kPh[(16 + lm) * 136 + off];
        s8v bl0 = *(const s8v*)&kPl[(0 + lm) * 136 + off];
        s8v bl1 = *(const s8v*)&kPl[(16 + lm) * 136 + off];
        acc[0] = __builtin_amdgcn_mfma_f32_16x16x32_bf16(ah0, bh0, acc[0], 0, 0, 0);
        acc[0] = __builtin_amdgcn_mfma_f32_16x16x32_bf16(ah0, bl0, acc[0], 0, 0, 0);
        acc[0] = __builtin_amdgcn_mfma_f32_16x16x32_bf16(al0, bh0, acc[0], 0, 0, 0);
        acc[1] = __builtin_amdgcn_mfma_f32_16x16x32_bf16(ah0, bh1, acc[1], 0, 0, 0);
        acc[1] = __builtin_amdgcn_mfma_f32_16x16x32_bf16(ah0, bl1, acc[1], 0, 0, 0);
        acc[1] = __builtin_amdgcn_mfma_f32_16x16x32_bf16(al0, bh1, acc[1], 0, 0, 0);
        acc[2] = __builtin_amdgcn_mfma_f32_16x16x32_bf16(ah1, bh0, acc[2], 0, 0, 0);
        acc[2] = __builtin_amdgcn_mfma_f32_16x16x32_bf16(ah1, bl0, acc[2], 0, 0, 0);
        acc[2] = __builtin_amdgcn_mfma_f32_16x16x32_bf16(al1, bh0, acc[2], 0, 0, 0);
        acc[3] = __builtin_amdgcn_mfma_f32_16x16x32_bf16(ah1, bh1, acc[3], 0, 0, 0);
        acc[3] = __builtin_amdgcn_mfma_f32_16x16x32_bf16(ah1, bl1, acc[3], 0, 0, 0);
        acc[3] = __builtin_amdgcn_mfma_f32_16x16x32_bf16(al1, bh1, acc[3], 0, 0, 0);
      } else {
        const int d0 = (wid - 2) * 32;
        s8v vh0 = *(const s8v*)&vTh[(d0 + lm) * 136 + off];
        s8v vh1 = *(const s8v*)&vTh[(d0 + 16 + lm) * 136 + off];
        s8v vl0 = *(const s8v*)&vTl[(d0 + lm) * 136 + off];
        s8v vl1 = *(const s8v*)&vTl[(d0 + 16 + lm) * 136 + off];
        s8v kh0 = *(const s8v*)&kCh[(0 + lm) * 136 + off];
        s8v kh1 = *(const s8v*)&kCh[(16 + lm) * 136 + off];
        s8v kl0 = *(const s8v*)&kCl[(0 + lm) * 136 + off];
        s8v kl1 = *(const s8v*)&kCl[(16 + lm) * 136 + off];
        acc[0] = __builtin_amdgcn_mfma_f32_16x16x32_bf16(vh0, kh0, acc[0], 0, 0, 0);
        acc[0] = __builtin_amdgcn_mfma_f32_16x16x32_bf16(vh0, kl0, acc[0], 0, 0, 0);
        acc[0] = __builtin_amdgcn_mfma_f32_16x16x32_bf16(vl0, kh0, acc[0], 0, 0, 0);
        acc[1] = __builtin_amdgcn_mfma_f32_16x16x32_bf16(vh0, kh1, acc[1], 0, 0, 0);
        acc[1] = __builtin_amdgcn_mfma_f32_16x16x32_bf16(vh0, kl1, acc[1], 0, 0, 0);
        acc[1] = __builtin_amdgcn_mfma_f32_16x16x32_bf16(vl0, kh1, acc[1], 0, 0, 0);
        acc[2] = __builtin_amdgcn_mfma_f32_16x16x32_bf16(vh1, kh0, acc[2], 0, 0, 0);
        acc[2] = __builtin_amdgcn_mfma_f32_16x16x32_bf16(vh1, kl0, acc[2], 0, 0, 0);
        acc[2] = __builtin_amdgcn_mfma_f32_16x16x32_bf16(vl1, kh0, acc[2], 0, 0, 0);
        acc[3] = __builtin_amdgcn_mfma_f32_16x16x32_bf16(vh1, kh1, acc[3], 0, 0, 0);
        acc[3] = __builtin_amdgcn_mfma_f32_16x16x32_bf16(vh1, kl1, acc[3], 0, 0, 0);
        acc[3] = __builtin_amdgcn_mfma_f32_16x16x32_bf16(vl1, kh1, acc[3], 0, 0, 0);
      }
    }
  }

  // write partials (D layout: col = lm, row = lq*4 + r)
  if (wid < 2) {
    float* dst = (wid == 0 ? Gp : Mp) + (size_t)(c * 64 + bh) * 1024;
#pragma unroll
    for (int t = 0; t < 4; t++) {
      int i0 = (t >> 1) * 16, j0 = (t & 1) * 16;
#pragma unroll
      for (int r = 0; r < 4; r++)
        dst[(i0 + lq * 4 + r) * 32 + j0 + lm] = acc[t][r];
    }
  } else {
    float* dst = Cp + (size_t)(c * 64 + bh) * 2048;
#pragma unroll
    for (int t = 0; t < 4; t++) {
      int d0 = (wid - 2) * 32 + (t >> 1) * 16, j0 = (t & 1) * 16;
#pragma unroll
      for (int r = 0; r < 4; r++)
        dst[(d0 + lq * 4 + r) * 32 + j0 + lm] = acc[t][r];
    }
  }
}

// ------- per-(b,h) operator: chol, G^{-1}, A_w, sigma, F = Cv*Gi*(s*M*Gi)^4 -------
// Tri-solves are register-resident (lane = column, fully unrolled -> no LDS
// write->read turnaround on the serial chain); Gi and L^{-1}M solves run
// CONCURRENTLY on wave0/wave1. Arithmetic order identical to block version.
__global__ __launch_bounds__(256) void solve_op_k(
    const float* __restrict__ Gp, const float* __restrict__ Mp,
    const float* __restrict__ Cp, const float* __restrict__ lridge,
    const float* __restrict__ lgamma, float* __restrict__ Ft) {
  __shared__ float Gs[32 * 33];
  __shared__ float Ms[32 * 32];
  __shared__ float Gi[32 * 32];
  __shared__ float W2s[32 * 33];
  __shared__ float Aw[32 * 33];
  __shared__ float Nn[32 * 32];
  __shared__ float N2[32 * 32];
  __shared__ float T1[32 * 32];
  __shared__ float Cs[64 * 32];
  __shared__ float red[256];
  const int bh = blockIdx.x;
  const int tid = threadIdx.x;
  const float ridge = expf(lridge[0]);

  for (int e = tid; e < 1024; e += 256) {
    int i = e >> 5, j = e & 31;
    float g = 0.f, m = 0.f;
#pragma unroll
    for (int cc = 0; cc < TCH; cc++) {
      g += Gp[(size_t)(cc * 64 + bh) * 1024 + e];
      m += Mp[(size_t)(cc * 64 + bh) * 1024 + e];
    }
    if (i == j) g += ridge;
    Gs[i * 33 + j] = g;
    Ms[e] = m;
  }
  for (int e = tid; e < 2048; e += 256) {
    float s = 0.f;
#pragma unroll
    for (int cc = 0; cc < TCH; cc++) s += Cp[(size_t)(cc * 64 + bh) * 2048 + e];
    Cs[e] = s;
  }
  __syncthreads();

  for (int j = 0; j < 32; j++) {
    float d = Gs[j * 33 + j];
    __syncthreads();
    float inv = 1.0f / sqrtf(d);
    if (tid >= j && tid < 32) Gs[tid * 33 + j] *= inv;
    __syncthreads();
    int w = 31 - j;
    for (int e = tid; e < w * w; e += 256) {
      int i = j + 1 + e / w, k = j + 1 + e % w;
      Gs[i * 33 + k] -= Gs[i * 33 + j] * Gs[k * 33 + j];
    }
    __syncthreads();
  }

  // wave0: Gi = G^{-1} (fwd+back on e_c); wave1: W2 = L^{-1} M (fwd). Concurrent.
  if (tid < 32) {
    const int c = tid;
    float w[32];
#pragma unroll
    for (int i = 0; i < 32; i++) {
      float s = (i == c) ? 1.0f : 0.0f;
#pragma unroll
      for (int j = 0; j < 32; j++)
        if (j < i) s -= Gs[i * 33 + j] * w[j];
      w[i] = s / Gs[i * 33 + i];
    }
#pragma unroll
    for (int i = 31; i >= 0; i--) {
      float s = w[i];
#pragma unroll
      for (int j = 0; j < 32; j++)
        if (j > i) s -= Gs[j * 33 + i] * w[j];
      w[i] = s / Gs[i * 33 + i];
    }
#pragma unroll
    for (int i = 0; i < 32; i++) Gi[i * 32 + c] = w[i];
  } else if (tid >= 64 && tid < 96) {
    const int c = tid - 64;
    float w[32];
#pragma unroll
    for (int i = 0; i < 32; i++) {
      float s = Ms[i * 32 + c];
#pragma unroll
      for (int j = 0; j < 32; j++)
        if (j < i) s -= Gs[i * 33 + j] * w[j];
      w[i] = s / Gs[i * 33 + i];
    }
#pragma unroll
    for (int i = 0; i < 32; i++) W2s[i * 33 + c] = w[i];
  }
  __syncthreads();
  // Aw (holds A_w^T; only norms consumed): column c solves L a = (L^{-1}M) row c
  if (tid < 32) {
    const int c = tid;
    float a[32];
#pragma unroll
    for (int i = 0; i < 32; i++) {
      float s = W2s[c * 33 + i];
#pragma unroll
      for (int j = 0; j < 32; j++)
        if (j < i) s -= Gs[i * 33 + j] * a[j];
      a[i] = s / Gs[i * 33 + i];
    }
#pragma unroll
    for (int i = 0; i < 32; i++) Aw[i * 33 + c] = a[i];
  }
  __syncthreads();

  float s0 = 0.0f;
  for (int e = tid; e < 1024; e += 256) {
    float a = Aw[(e >> 5) * 33 + (e & 31)];
    s0 += a * a;
  }
  red[tid] = s0;
  __syncthreads();
  for (int off = 128; off > 0; off >>= 1) {
    if (tid < off) red[tid] += red[tid + off];
    __syncthreads();
  }
  float frob2 = red[0];
  float sigma;
  if (frob2 <= 1.0f) {
    sigma = sqrtf(frob2);
  } else {
    // in-wave power iteration, LDS reads (no register arrays -> no spill risk)
    if (tid < 32) {
      const int i = tid;
      float v = 1.0f + 0.001f * (float)i;
      float sig = 0.0f, prev = -1.0f;
      for (int it = 0; it < 64; it++) {
        float u = 0.0f;
#pragma unroll
        for (int j = 0; j < 32; j++) u += Aw[i * 33 + j] * __shfl(v, j, 64);
        float n2 = u * u;
#pragma unroll
        for (int o = 16; o > 0; o >>= 1) n2 += __shfl_xor(n2, o, 64);
        u /= fmaxf(sqrtf(n2), 1e-30f);
        float vn = 0.0f;
#pragma unroll
        for (int j = 0; j < 32; j++) vn += Aw[j * 33 + i] * __shfl(u, j, 64);
        float m2 = vn * vn;
#pragma unroll
        for (int o = 16; o > 0; o >>= 1) m2 += __shfl_xor(m2, o, 64);
        sig = sqrtf(m2);
        v = vn / fmaxf(sig, 1e-30f);
        if (it >= 7 && fabsf(sig - prev) <= 1e-7f * sig) break;
        prev = sig;
      }
      if (i == 0) red[0] = sig;
    }
    __syncthreads();
    sigma = red[0];
  }
  float gamma_c = fminf(expf(lgamma[0]), 1.0f);
  float scale = gamma_c / fmaxf(fmaxf(sigma, 1e-8f), 1.0f);

  for (int e = tid; e < 1024; e += 256) {
    int i = e >> 5, c = e & 31;
    float s = 0;
#pragma unroll
    for (int k = 0; k < 32; k++) s += Ms[i * 32 + k] * Gi[k * 32 + c];
    Nn[e] = scale * s;
  }
  __syncthreads();
  for (int e = tid; e < 1024; e += 256) {
    int i = e >> 5, c = e & 31;
    float s = 0;
#pragma unroll
    for (int k = 0; k < 32; k++) s += Nn[i * 32 + k] * Nn[k * 32 + c];
    N2[e] = s;
  }
  __syncthreads();
  for (int e = tid; e < 1024; e += 256) {
    int i = e >> 5, c = e & 31;
    float s = 0;
#pragma unroll
    for (int k = 0; k < 32; k++) s += N2[i * 32 + k] * N2[k * 32 + c];
    Ms[e] = s;
  }
  __syncthreads();
  for (int e = tid; e < 1024; e += 256) {
    int i = e >> 5, c = e & 31;
    float s = 0;
#pragma unroll
    for (int k = 0; k < 32; k++) s += Gi[i * 32 + k] * Ms[k * 32 + c];
    T1[e] = s;
  }
  __syncthreads();
  for (int e = tid; e < 2048; e += 256) {
    int j = e >> 6, d = e & 63;
    float s = 0;
#pragma unroll
    for (int k = 0; k < 32; k++) s += Cs[d * 32 + k] * T1[k * 32 + j];
    Ft[(size_t)bh * 2048 + e] = s;
  }
}

// ------------- apply F^T per (head, 128-token chunk) -> full_hi (bf16) -------------
// FH written chunk-swizzled within each head's 64-col group (gemm_out consumes).
__global__ __launch_bounds__(256) void apply_k(const float* __restrict__ Y1,
                                               const float* __restrict__ Ft,
                                               unsigned short* __restrict__ FH) {
  __shared__ float xs[128 * 32];
  const int h = blockIdx.y;
  const int r0 = blockIdx.x * 128;
  const int bh = (r0 >> 12) * NH + h;
  const int tid = threadIdx.x;
  const int d = tid & 63, t0 = tid >> 6;
  float fcol[32];
  const float* fb = &Ft[(size_t)bh * 2048 + d];
#pragma unroll
  for (int j = 0; j < 32; j++) fcol[j] = fb[j * 64];
  for (int e = tid; e < 1024; e += 256) {
    int row = e >> 3, j4 = (e & 7) << 2;
    *(float4*)&xs[row * 32 + j4] =
        *(const float4*)&Y1[((size_t)(r0 + row)) * 512 + h * 32 + j4];
  }
  __syncthreads();
  const int dq = d >> 3, dr = d & 7;
  for (int tl = t0; tl < 128; tl += 4) {
    float s = 0;
#pragma unroll
    for (int j = 0; j < 32; j++) s += xs[tl * 32 + j] * fcol[j];
    int col = h * 64 + ((dq ^ (tl & 7)) << 3) + dr;
    FH[((size_t)(r0 + tl)) * 1024 + col] = bf16_rne(s);
  }
}

// ------------- output GEMM (MFMA): out = sg * full @ Wo ; A=hi, B=hi+lo -------------
// 256x128 tile, BK=64, 8 waves, double-buffered LDS, counted vmcnt (never 0 in
// steady state), pre-swizzled-global + swizzled ds_read (bank-floor reads).
__global__ __launch_bounds__(512) void gemm_out_k(
    const unsigned short* __restrict__ FH,
    const unsigned short* __restrict__ WThi, const unsigned short* __restrict__ WTlo,
    const float* __restrict__ alpha, float* __restrict__ out) {
  __shared__ __align__(16) unsigned short lds[65536];  // 128 KB: A 2x32K, Bh 2x16K, Bl 2x16K
  int xx, yy, zz;
  xcd_swz(8, 64, xx, yy, zz);
  const int m0 = yy * 256;
  const int n0 = xx * 128;
  const int tid = threadIdx.x;
  const int lane = tid & 63;
  const int wid  = tid >> 6;                 // 0..7
  const int wm = (wid >> 1) * 64;            // 4 M-waves x 64 rows
  const int wn = (wid & 1) * 64;             // 2 N-waves x 64 cols
  const int lm = lane & 15, lq = lane >> 4;
  const int l8 = lane >> 3, c8 = (lane & 7) << 3;  // staging: 8 rows x 8 chunks per issue

  f4v acc[4][4];
#pragma unroll
  for (int i = 0; i < 4; i++)
#pragma unroll
    for (int j = 0; j < 4; j++) acc[i][j] = (f4v){0.f, 0.f, 0.f, 0.f};

  auto STAGE = [&](int t, int buf) {
    const int kt = t * 64;
#pragma unroll
    for (int i = 0; i < 4; i++) {            // A: 4 issues/wave (32 total)
      int iss = wid * 4 + i;
      gll16(&lds[buf * 16384 + iss * 512],
            &FH[(size_t)(m0 + iss * 8 + l8) * 1024 + kt + c8]);
    }
#pragma unroll
    for (int i = 0; i < 2; i++) {            // Bh: 2 issues/wave (16 total)
      int iss = wid * 2 + i;
      gll16(&lds[32768 + buf * 8192 + iss * 512],
            &WThi[(size_t)(n0 + iss * 8 + l8) * 1024 + kt + c8]);
    }
#pragma unroll
    for (int i = 0; i < 2; i++) {            // Bl
      int iss = wid * 2 + i;
      gll16(&lds[49152 + buf * 8192 + iss * 512],
            &WTlo[(size_t)(n0 + iss * 8 + l8) * 1024 + kt + c8]);
    }
  };

  STAGE(0, 0);
  STAGE(1, 1);

  for (int t = 0; t < 16; t++) {
    const int buf = t & 1;
    if (t < 15) asm volatile("s_waitcnt vmcnt(8)" ::: "memory");
    else        asm volatile("s_waitcnt vmcnt(0)" ::: "memory");
    __builtin_amdgcn_s_barrier();
    const unsigned short* Ab  = &lds[buf * 16384];
    const unsigned short* Bhb = &lds[32768 + buf * 8192];
    const unsigned short* Blb = &lds[49152 + buf * 8192];
    __builtin_amdgcn_s_setprio(1);
#pragma unroll
    for (int kk = 0; kk < 2; kk++) {
      s8v ah[4], bh[4], bl[4];
#pragma unroll
      for (int i = 0; i < 4; i++) {
        int rA = wm + i * 16 + lm;
        int rB = wn + i * 16 + lm;
        int sA = (((kk * 4 + lq) ^ (rA & 7)) << 3);
        int sB = (((kk * 4 + lq) ^ (rB & 7)) << 3);
        ah[i] = *(const s8v*)&Ab[rA * 64 + sA];
        bh[i] = *(const s8v*)&Bhb[rB * 64 + sB];
        bl[i] = *(const s8v*)&Blb[rB * 64 + sB];
      }
#pragma unroll
      for (int mi = 0; mi < 4; mi++)
#pragma unroll
        for (int ni = 0; ni < 4; ni++) {
          acc[mi][ni] = __builtin_amdgcn_mfma_f32_16x16x32_bf16(ah[mi], bh[ni], acc[mi][ni], 0, 0, 0);
          acc[mi][ni] = __builtin_amdgcn_mfma_f32_16x16x32_bf16(ah[mi], bl[ni], acc[mi][ni], 0, 0, 0);
        }
    }
    __builtin_amdgcn_s_setprio(0);
    __builtin_amdgcn_sched_barrier(0);
    __builtin_amdgcn_s_barrier();
    if (t < 14) STAGE(t + 2, buf);
  }

  float sg = 1.0f / (1.0f + expf(-alpha[0]));
#pragma unroll
  for (int mi = 0; mi < 4; mi++)
#pragma unroll
    for (int r = 0; r < 4; r++) {
      size_t orow = (size_t)(m0 + wm + mi * 16 + lq * 4 + r);
#pragma unroll
      for (int ni = 0; ni < 4; ni++)
        out[orow * 1024 + n0 + wn + ni * 16 + lm] = sg * acc[mi][ni][r];
    }
}

extern "C" void kernel_launch(void* const* d_in, const int* in_sizes, int n_in,
                              void* d_out, int out_size, void* d_ws, size_t ws_size,
                              hipStream_t stream) {
  const float* X      = (const float*)d_in[0];
  const float* Wk     = (const float*)d_in[1];
  const float* Wq     = (const float*)d_in[2];
  const float* Wv     = (const float*)d_in[3];
  const float* Wo     = (const float*)d_in[4];
  const float* lng    = (const float*)d_in[5];
  const float* lnb    = (const float*)d_in[6];
  const float* alpha  = (const float*)d_in[7];
  const float* lridge = (const float*)d_in[8];
  const float* lgamma = (const float*)d_in[9];
  const int*   pref   = (const int*)d_in[10];
  float* out = (float*)d_out;
  char* ws = (char*)d_ws;
  float* stats = (float*)(ws + OFF_STATS);
  float* Gp    = (float*)(ws + OFF_GP);
  float* Mp    = (float*)(ws + OFF_MP);
  float* Cp    = (float*)(ws + OFF_CP);
  float* Ft    = (float*)(ws + OFF_FT);
  unsigned short* WKH = (unsigned short*)(ws + OFF_WKH);
  unsigned short* WKL = (unsigned short*)(ws + OFF_WKL);
  unsigned short* WQH = (unsigned short*)(ws + OFF_WQH);
  unsigned short* WQL = (unsigned short*)(ws + OFF_WQL);
  unsigned short* WVH = (unsigned short*)(ws + OFF_WVH);
  unsigned short* WVL = (unsigned short*)(ws + OFF_WVL);
  unsigned short* WOH = (unsigned short*)(ws + OFF_WOH);
  unsigned short* WOL = (unsigned short*)(ws + OFF_WOL);
  float* Y1 = (float*)(ws + OFF_Y1);
  float* Y2 = (float*)(ws + OFF_Y2);
  unsigned short* FH = (unsigned short*)(ws + OFF_FH);

  ln_stats_k<<<16384, 256, 0, stream>>>(X, stats);
  prep_w_k<<<dim3(16, 32), 256, 0, stream>>>(Wk, 512, WKH, WKL, 2);
  prep_w_k<<<dim3(16, 32), 256, 0, stream>>>(Wq, 512, WQH, WQL, 2);
  prep_w_k<<<dim3(32, 32), 256, 0, stream>>>(Wv, 1024, WVH, WVL, 2);
  prep_w_k<<<dim3(32, 32), 256, 0, stream>>>(Wo, 1024, WOH, WOL, 1);
  gemm_ln_k<<<dim3(2, 32, NB), 512, 0, stream>>>(X, stats, lng, lnb,
      WKH, WKL, WQH, WQL, pref, 0, 512, Y1);
  gemm_ln_k<<<dim3(4, 32, NB), 512, 0, stream>>>(X, stats, lng, lnb,
      WVH, WVL, WVH, WVL, pref, 2, 1024, Y2);
  build_gmc_mfma_k<<<dim3(TCH, 64), 256, 0, stream>>>(Y1, Y2, pref, Gp, Mp, Cp);
  solve_op_k<<<64, 256, 0, stream>>>(Gp, Mp, Cp, lridge, lgamma, Ft);
  apply_k<<<dim3(128, NH), 256, 0, stream>>>(Y1, Ft, FH);
  gemm_out_k<<<dim3(8, 64), 512, 0, stream>>>(FH, WOH, WOL, alpha, out);
}

// Round 9
// 415.093 us; speedup vs baseline: 1.1424x; 1.0092x over previous
//
#include <hip/hip_runtime.h>
#include <math.h>

#define D_MODEL 1024
#define TT 4096
#define NB 4
#define NH 16
#define TCH 8

typedef __attribute__((ext_vector_type(8))) short s8v;
typedef __attribute__((ext_vector_type(4))) float f4v;
typedef __attribute__((ext_vector_type(8))) unsigned short u16x8;

// ---- workspace layout (bytes); peak ~88 MB (proven budget 100 MB) ----
#define OFF_STATS ((size_t)0)
#define OFF_GP    ((size_t)(1) << 20)    // 8*64*1024*4 = 2 MB partials
#define OFF_MP    ((size_t)(3) << 20)    // 2 MB
#define OFF_CP    ((size_t)(5) << 20)    // 8*64*2048*4 = 4 MB
#define OFF_FT    ((size_t)(9) << 20)    // 512 KB
#define OFF_WKH   ((size_t)(10) << 20)
#define OFF_WKL   ((size_t)(11) << 20)
#define OFF_WQH   ((size_t)(12) << 20)
#define OFF_WQL   ((size_t)(13) << 20)
#define OFF_WVH   ((size_t)(14) << 20)
#define OFF_WVL   ((size_t)(16) << 20)
#define OFF_WOH   ((size_t)(18) << 20)
#define OFF_WOL   ((size_t)(20) << 20)
#define OFF_Y1    ((size_t)(22) << 20)   // 32 MB
#define OFF_Y2    ((size_t)(54) << 20)   // P*NB*1024*4; FH overlays after build_gmc
#define OFF_FH    OFF_Y2

__device__ __forceinline__ unsigned short bf16_rne(float x) {
  unsigned u = __float_as_uint(x);
  return (unsigned short)((u + 0x7fffu + ((u >> 16) & 1u)) >> 16);
}
__device__ __forceinline__ void split_bf16(float x, unsigned short& h, unsigned short& l) {
  unsigned u = __float_as_uint(x);
  unsigned r = (u + 0x7fffu + ((u >> 16) & 1u)) & 0xffff0000u;
  h = (unsigned short)(r >> 16);
  float res = x - __uint_as_float(r);
  l = bf16_rne(res);
}

// async global->LDS, 16 B per lane; lds base must be wave-uniform (HW adds lane*16)
__device__ __forceinline__ void gll16(unsigned short* lds, const unsigned short* g) {
  __builtin_amdgcn_global_load_lds(
      (__attribute__((address_space(1))) void*)(void*)(g),
      (__attribute__((address_space(3))) void*)(lds), 16, 0, 0);
}

// bijective XCD swizzle: the gx blocks sharing one (y,z) land consecutively on ONE
// XCD; (y,z) values strided by 8 across XCDs (keeps P-masked kernels balanced).
__device__ __forceinline__ void xcd_swz(int gx, int gy, int& x, int& y, int& z) {
  int wg = blockIdx.x + gx * (blockIdx.y + gy * blockIdx.z);
  int k = wg & 7, j = wg >> 3;
  x = j % gx;
  int yz = k + ((j / gx) << 3);
  y = yz % gy;
  z = yz / gy;
}

// ---------------- LayerNorm statistics: one block per row ----------------
__global__ __launch_bounds__(256) void ln_stats_k(const float* __restrict__ X,
                                                  float* __restrict__ stats) {
  int r = blockIdx.x;
  const float4 v = ((const float4*)(X + (size_t)r * D_MODEL))[threadIdx.x];
  float s  = v.x + v.y + v.z + v.w;
  float ss = v.x * v.x + v.y * v.y + v.z * v.z + v.w * v.w;
#pragma unroll
  for (int off = 32; off > 0; off >>= 1) {
    s  += __shfl_down(s, off, 64);
    ss += __shfl_down(ss, off, 64);
  }
  __shared__ float as_[4], bs_[4];
  int w = threadIdx.x >> 6, lane = threadIdx.x & 63;
  if (lane == 0) { as_[w] = s; bs_[w] = ss; }
  __syncthreads();
  if (threadIdx.x == 0) {
    float S  = as_[0] + as_[1] + as_[2] + as_[3];
    float SS = bs_[0] + bs_[1] + bs_[2] + bs_[3];
    float mu  = S * (1.0f / D_MODEL);
    float var = SS * (1.0f / D_MODEL) - mu * mu;
    stats[2 * (size_t)r]     = mu;
    stats[2 * (size_t)r + 1] = 1.0f / sqrtf(var + 1e-5f);
  }
}

// ------- prep: transpose W[K][N] -> WT_hi/lo [N][K] bf16 split -------
// swz=2: XOR 16B-chunk idx with (row>>1)&3 within 32-col groups (all GEMM consumers).
__global__ __launch_bounds__(256) void prep_w_k(const float* __restrict__ W, int N,
                                                unsigned short* __restrict__ Thi,
                                                unsigned short* __restrict__ Tlo,
                                                int swz) {
  __shared__ float tileT[32 * 33];
  const int n0 = blockIdx.x * 32, k0 = blockIdx.y * 32;
  const int tid = threadIdx.x;
  {
    int k_l = tid >> 3, n4 = (tid & 7) << 2;
    float4 v = *(const float4*)&W[(size_t)(k0 + k_l) * N + n0 + n4];
    tileT[(n4 + 0) * 33 + k_l] = v.x;
    tileT[(n4 + 1) * 33 + k_l] = v.y;
    tileT[(n4 + 2) * 33 + k_l] = v.z;
    tileT[(n4 + 3) * 33 + k_l] = v.w;
  }
  __syncthreads();
  {
    int n_l = tid >> 3, k4 = (tid & 7) << 2;
    unsigned short h[4], l[4];
#pragma unroll
    for (int i = 0; i < 4; i++) split_bf16(tileT[n_l * 33 + k4 + i], h[i], l[i]);
    int kc = k0 + k4;
    int col = kc;
    if (swz == 2)
      col = (kc & ~31) | ((((kc >> 3) & 3) ^ ((n_l >> 1) & 3)) << 3) | (kc & 7);
    *(ushort4*)&Thi[(size_t)(n0 + n_l) * 1024 + col] = make_ushort4(h[0], h[1], h[2], h[3]);
    *(ushort4*)&Tlo[(size_t)(n0 + n_l) * 1024 + col] = make_ushort4(l[0], l[1], l[2], l[3]);
  }
}

// ------- fused LN + projection GEMM, deep-pipelined (counted vmcnt) -------
// 128x256 tile, BK=32, 512 thr, 8 waves (2Mx4N, 64x64/wave). B hi/lo double-
// buffered via global_load_lds (pre-swizzled global, swizzled ds_read); A (LN+
// split) reg-pipelined one tile ahead (xE/xO static sets). 6 VMEM/wave/iter ->
// steady-state s_waitcnt vmcnt(6), never 0. MFMA order bit-identical to the
// 2-barrier version. mode 0: K/Q merged -> Y1; mode 2: V -> Y2 compact.
__global__ __launch_bounds__(512) void gemm_ln_k(
    const float* __restrict__ X, const float* __restrict__ stats,
    const float* __restrict__ lng, const float* __restrict__ lnb,
    const unsigned short* __restrict__ BH0, const unsigned short* __restrict__ BL0,
    const unsigned short* __restrict__ BH1, const unsigned short* __restrict__ BL1,
    const int* __restrict__ pref, int mode, int Nw, float* __restrict__ Y) {
  int P = pref[0]; P = P < 1 ? 1 : (P > TT - 1 ? TT - 1 : P);
  int xx, yy, zz;
  xcd_swz(gridDim.x, 32, xx, yy, zz);
  const int b  = zz;
  const int t0 = yy * 128;
  const int n0 = xx * 256;
  if (mode == 2 && t0 >= P) return;
  const int row0 = b * TT + t0;
  const bool hasK = (t0 < P);
  const bool hasQ = (t0 + 128 > P);

  __shared__ __align__(16) unsigned short aH[2 * 128 * 40], aL[2 * 128 * 40];
  __shared__ __align__(16) unsigned short bH[2 * 256 * 32], bL[2 * 256 * 32];
  __shared__ float lngs[1024], lnbs[1024];

  const int tid = threadIdx.x;
  const int lane = tid & 63;
  const int wid  = tid >> 6;
  const int wm = (wid >> 2) * 64, wn = (wid & 3) * 64;
  const int lm = lane & 15, lq = lane >> 4;
  const int arow = tid >> 2, acol = (tid & 3) << 3;   // A stage: 128 rows x 4 chunks
  const int l4 = lane >> 2, c4 = (lane & 3) << 3;     // B stage: 16 rows x 4 chunks

  for (int e = tid; e < 1024; e += 512) { lngs[e] = lng[e]; lnbs[e] = lnb[e]; }
  const float mu = stats[2 * (size_t)(row0 + arow)];
  const float rs = stats[2 * (size_t)(row0 + arow) + 1];

  for (int pass = 0; pass < 2; ++pass) {
    if (mode == 2) { if (pass == 1) break; }
    else { if (pass == 0 && !hasK) continue; if (pass == 1 && !hasQ) continue; }
    const unsigned short* WH = pass ? BH1 : BH0;
    const unsigned short* WL = pass ? BL1 : BL0;

    f4v acc[4][4];
#pragma unroll
    for (int i = 0; i < 4; i++)
#pragma unroll
      for (int j = 0; j < 4; j++) acc[i][j] = (f4v){0.f, 0.f, 0.f, 0.f};

    float4 xE[2], xO[2];

    auto XLOAD = [&](int t, float4 (&xr)[2]) {
      const float* src = &X[(size_t)(row0 + arow) * 1024 + t * 32 + acol];
      xr[0] = *(const float4*)src;
      xr[1] = *(const float4*)(src + 4);
    };
    auto STAGEB = [&](int t, int buf) {
      const int kt = t * 32;
#pragma unroll
      for (int i = 0; i < 2; i++) {
        int iss = wid * 2 + i;
        int r = n0 + iss * 16 + l4;
        gll16(&bH[buf * 8192 + iss * 512], &WH[(size_t)r * 1024 + kt + c4]);
        gll16(&bL[buf * 8192 + iss * 512], &WL[(size_t)r * 1024 + kt + c4]);
      }
    };
    auto LNW = [&](int tt, float4 (&xr)[2], int abuf) {
      const int kt = tt * 32;
      float4 lg0 = *(const float4*)&lngs[kt + acol];
      float4 lg1 = *(const float4*)&lngs[kt + acol + 4];
      float4 lb0 = *(const float4*)&lnbs[kt + acol];
      float4 lb1 = *(const float4*)&lnbs[kt + acol + 4];
      float xv[8] = {xr[0].x, xr[0].y, xr[0].z, xr[0].w,
                     xr[1].x, xr[1].y, xr[1].z, xr[1].w};
      float lgv[8] = {lg0.x, lg0.y, lg0.z, lg0.w, lg1.x, lg1.y, lg1.z, lg1.w};
      float lbv[8] = {lb0.x, lb0.y, lb0.z, lb0.w, lb1.x, lb1.y, lb1.z, lb1.w};
      u16x8 hv, lv;
#pragma unroll
      for (int i = 0; i < 8; i++) {
        float nv = (xv[i] - mu) * rs * lgv[i] + lbv[i];
        unsigned short h, l;
        split_bf16(nv, h, l);
        hv[i] = h; lv[i] = l;
      }
      int ao = abuf * 5120 + arow * 40 + acol;
      *(u16x8*)&aH[ao] = hv;
      *(u16x8*)&aL[ao] = lv;
    };

    auto ITER = [&](int t, float4 (&xrd)[2], float4 (&xwr)[2]) {
      const int buf = t & 1;
      asm volatile("s_waitcnt vmcnt(6)" ::: "memory");
      __builtin_amdgcn_s_barrier();
      s8v ah[4], al[4], bh[4], bl[4];
#pragma unroll
      for (int i = 0; i < 4; i++) {
        int rA = wm + i * 16 + lm;
        int rB = wn + i * 16 + lm;
        int ao = buf * 5120 + rA * 40 + lq * 8;
        int bo = buf * 8192 + rB * 32 + ((lq ^ ((rB >> 1) & 3)) << 3);
        ah[i] = *(const s8v*)&aH[ao];
        al[i] = *(const s8v*)&aL[ao];
        bh[i] = *(const s8v*)&bH[bo];
        bl[i] = *(const s8v*)&bL[bo];
      }
      __builtin_amdgcn_s_setprio(1);
#pragma unroll
      for (int mi = 0; mi < 4; mi++)
#pragma unroll
        for (int ni = 0; ni < 4; ni++) {
          acc[mi][ni] = __builtin_amdgcn_mfma_f32_16x16x32_bf16(ah[mi], bh[ni], acc[mi][ni], 0, 0, 0);
          acc[mi][ni] = __builtin_amdgcn_mfma_f32_16x16x32_bf16(ah[mi], bl[ni], acc[mi][ni], 0, 0, 0);
          acc[mi][ni] = __builtin_amdgcn_mfma_f32_16x16x32_bf16(al[mi], bh[ni], acc[mi][ni], 0, 0, 0);
        }
      __builtin_amdgcn_s_setprio(0);
      if (t < 31) LNW(t + 1, xrd, buf ^ 1);
      asm volatile("s_waitcnt lgkmcnt(0)" ::: "memory");
      __builtin_amdgcn_s_barrier();
      if (t < 30) {
        XLOAD(t + 2, xwr);
        STAGEB(t + 2, buf);
      }
    };

    // prologue
    XLOAD(0, xE); STAGEB(0, 0);
    XLOAD(1, xO); STAGEB(1, 1);
    __syncthreads();              // drain + publish lngs/lnbs
    LNW(0, xE, 0);
    __syncthreads();              // publish A(0)

    for (int t2 = 0; t2 < 32; t2 += 2) {
      ITER(t2,     xO, xE);       // even iter: LNW reads xO, XLOAD fills xE
      ITER(t2 + 1, xE, xO);
    }

#pragma unroll
    for (int mi = 0; mi < 4; mi++) {
#pragma unroll
      for (int r = 0; r < 4; r++) {
        int t = t0 + wm + mi * 16 + lq * 4 + r;
        bool ok = (mode == 2) ? (t < P) : (pass ? (t >= P) : (t < P));
        if (!ok) continue;
        size_t orow = (mode == 2) ? ((size_t)b * P + t) : ((size_t)b * TT + t);
#pragma unroll
        for (int ni = 0; ni < 4; ni++)
          Y[orow * Nw + n0 + wn + ni * 16 + lm] = acc[mi][ni][r];
      }
    }
  }
}

// ------------- G, M, C_v Gram reductions via MFMA (partials, no atomics) -------------
__global__ __launch_bounds__(256) void build_gmc_mfma_k(
    const float* __restrict__ Y1, const float* __restrict__ Y2,
    const int* __restrict__ pref,
    float* __restrict__ Gp, float* __restrict__ Mp, float* __restrict__ Cp) {
  int P = pref[0]; P = P < 1 ? 1 : (P > TT - 1 ? TT - 1 : P);
  const int c  = blockIdx.x;
  const int bh = blockIdx.y;
  const int b = bh >> 4, h = bh & 15;
  const int chunk = (P + TCH - 1) / TCH;
  const int tb = c * chunk;
  const int te = min(tb + chunk, P);

  __shared__ __align__(16) unsigned short kCh[32 * 136], kCl[32 * 136];
  __shared__ __align__(16) unsigned short kPh[32 * 136], kPl[32 * 136];
  __shared__ __align__(16) unsigned short vTh[64 * 136], vTl[64 * 136];

  const int tid = threadIdx.x;
  const int wid = tid >> 6, lane = tid & 63;
  const int lm = lane & 15, lq = lane >> 4;

  f4v acc[4];
#pragma unroll
  for (int i = 0; i < 4; i++) acc[i] = (f4v){0.f, 0.f, 0.f, 0.f};

  for (int t0 = tb; t0 < te; t0 += 128) {
    const int len = (te - t0 < 128) ? (te - t0) : 128;
    __syncthreads();
    // stage keys: rows 0..128 map t = t0-1+row; kC[u=row-1] current, kP[u=row] prev
    for (int e = tid; e < 129 * 8; e += 256) {
      int row = e >> 3, j4 = (e & 7) << 2;
      int t = t0 - 1 + row;
      float4 kv = make_float4(0.f, 0.f, 0.f, 0.f);
      if (row <= len && t >= 0)
        kv = *(const float4*)&Y1[((size_t)b * TT + t) * 512 + h * 32 + j4];
      unsigned short hh[4], ll[4];
      split_bf16(kv.x, hh[0], ll[0]); split_bf16(kv.y, hh[1], ll[1]);
      split_bf16(kv.z, hh[2], ll[2]); split_bf16(kv.w, hh[3], ll[3]);
      if (row >= 1) {
#pragma unroll
        for (int q = 0; q < 4; q++) {
          kCh[(j4 + q) * 136 + row - 1] = hh[q];
          kCl[(j4 + q) * 136 + row - 1] = ll[q];
        }
      }
      if (row < 128) {
#pragma unroll
        for (int q = 0; q < 4; q++) {
          kPh[(j4 + q) * 136 + row] = hh[q];
          kPl[(j4 + q) * 136 + row] = ll[q];
        }
      }
    }
    // stage values: v_t[d] at u = row
    for (int e = tid; e < 128 * 16; e += 256) {
      int row = e >> 4, dj = (e & 15) << 2;
      int t = t0 + row;
      float4 vv = make_float4(0.f, 0.f, 0.f, 0.f);
      if (row < len)
        vv = *(const float4*)&Y2[((size_t)b * P + t) * 1024 + h * 64 + dj];
      unsigned short hh[4], ll[4];
      split_bf16(vv.x, hh[0], ll[0]); split_bf16(vv.y, hh[1], ll[1]);
      split_bf16(vv.z, hh[2], ll[2]); split_bf16(vv.w, hh[3], ll[3]);
#pragma unroll
      for (int q = 0; q < 4; q++) {
        vTh[(dj + q) * 136 + row] = hh[q];
        vTl[(dj + q) * 136 + row] = ll[q];
      }
    }
    __syncthreads();

#pragma unroll
    for (int kk = 0; kk < 128; kk += 32) {
      const int off = kk + lq * 8;
      if (wid == 0) {
        s8v h0 = *(const s8v*)&kCh[(0 + lm) * 136 + off];
        s8v h1 = *(const s8v*)&kCh[(16 + lm) * 136 + off];
        s8v l0 = *(const s8v*)&kCl[(0 + lm) * 136 + off];
        s8v l1 = *(const s8v*)&kCl[(16 + lm) * 136 + off];
        acc[0] = __builtin_amdgcn_mfma_f32_16x16x32_bf16(h0, h0, acc[0], 0, 0, 0);
        acc[0] = __builtin_amdgcn_mfma_f32_16x16x32_bf16(h0, l0, acc[0], 0, 0, 0);
        acc[0] = __builtin_amdgcn_mfma_f32_16x16x32_bf16(l0, h0, acc[0], 0, 0, 0);
        acc[1] = __builtin_amdgcn_mfma_f32_16x16x32_bf16(h0, h1, acc[1], 0, 0, 0);
        acc[1] = __builtin_amdgcn_mfma_f32_16x16x32_bf16(h0, l1, acc[1], 0, 0, 0);
        acc[1] = __builtin_amdgcn_mfma_f32_16x16x32_bf16(l0, h1, acc[1], 0, 0, 0);
        acc[2] = __builtin_amdgcn_mfma_f32_16x16x32_bf16(h1, h0, acc[2], 0, 0, 0);
        acc[2] = __builtin_amdgcn_mfma_f32_16x16x32_bf16(h1, l0, acc[2], 0, 0, 0);
        acc[2] = __builtin_amdgcn_mfma_f32_16x16x32_bf16(l1, h0, acc[2], 0, 0, 0);
        acc[3] = __builtin_amdgcn_mfma_f32_16x16x32_bf16(h1, h1, acc[3], 0, 0, 0);
        acc[3] = __builtin_amdgcn_mfma_f32_16x16x32_bf16(h1, l1, acc[3], 0, 0, 0);
        acc[3] = __builtin_amdgcn_mfma_f32_16x16x32_bf16(l1, h1, acc[3], 0, 0, 0);
      } else if (wid == 1) {
        s8v ah0 = *(const s8v*)&kCh[(0 + lm) * 136 + off];
        s8v ah1 = *(const s8v*)&kCh[(16 + lm) * 136 + off];
        s8v al0 = *(const s8v*)&kCl[(0 + lm) * 136 + off];
        s8v al1 = *(const s8v*)&kCl[(16 + lm) * 136 + off];
        s8v bh0 = *(const s8v*)&kPh[(0 + lm) * 136 + off];
        s8v bh1 = *(const s8v*)&kPh[(16 + lm) * 136 + off];
        s8v bl0 = *(const s8v*)&kPl[(0 + lm) * 136 + off];
        s8v bl1 = *(const s8v*)&kPl[(16 + lm) * 136 + off];
        acc[0] = __builtin_amdgcn_mfma_f32_16x16x32_bf16(ah0, bh0, acc[0], 0, 0, 0);
        acc[0] = __builtin_amdgcn_mfma_f32_16x16x32_bf16(ah0, bl0, acc[0], 0, 0, 0);
        acc[0] = __builtin_amdgcn_mfma_f32_16x16x32_bf16(al0, bh0, acc[0], 0, 0, 0);
        acc[1] = __builtin_amdgcn_mfma_f32_16x16x32_bf16(ah0, bh1, acc[1], 0, 0, 0);
        acc[1] = __builtin_amdgcn_mfma_f32_16x16x32_bf16(ah0, bl1, acc[1], 0, 0, 0);
        acc[1] = __builtin_amdgcn_mfma_f32_16x16x32_bf16(al0, bh1, acc[1], 0, 0, 0);
        acc[2] = __builtin_amdgcn_mfma_f32_16x16x32_bf16(ah1, bh0, acc[2], 0, 0, 0);
        acc[2] = __builtin_amdgcn_mfma_f32_16x16x32_bf16(ah1, bl0, acc[2], 0, 0, 0);
        acc[2] = __builtin_amdgcn_mfma_f32_16x16x32_bf16(al1, bh0, acc[2], 0, 0, 0);
        acc[3] = __builtin_amdgcn_mfma_f32_16x16x32_bf16(ah1, bh1, acc[3], 0, 0, 0);
        acc[3] = __builtin_amdgcn_mfma_f32_16x16x32_bf16(ah1, bl1, acc[3], 0, 0, 0);
        acc[3] = __builtin_amdgcn_mfma_f32_16x16x32_bf16(al1, bh1, acc[3], 0, 0, 0);
      } else {
        const int d0 = (wid - 2) * 32;
        s8v vh0 = *(const s8v*)&vTh[(d0 + lm) * 136 + off];
        s8v vh1 = *(const s8v*)&vTh[(d0 + 16 + lm) * 136 + off];
        s8v vl0 = *(const s8v*)&vTl[(d0 + lm) * 136 + off];
        s8v vl1 = *(const s8v*)&vTl[(d0 + 16 + lm) * 136 + off];
        s8v kh0 = *(const s8v*)&kCh[(0 + lm) * 136 + off];
        s8v kh1 = *(const s8v*)&kCh[(16 + lm) * 136 + off];
        s8v kl0 = *(const s8v*)&kCl[(0 + lm) * 136 + off];
        s8v kl1 = *(const s8v*)&kCl[(16 + lm) * 136 + off];
        acc[0] = __builtin_amdgcn_mfma_f32_16x16x32_bf16(vh0, kh0, acc[0], 0, 0, 0);
        acc[0] = __builtin_amdgcn_mfma_f32_16x16x32_bf16(vh0, kl0, acc[0], 0, 0, 0);
        acc[0] = __builtin_amdgcn_mfma_f32_16x16x32_bf16(vl0, kh0, acc[0], 0, 0, 0);
        acc[1] = __builtin_amdgcn_mfma_f32_16x16x32_bf16(vh0, kh1, acc[1], 0, 0, 0);
        acc[1] = __builtin_amdgcn_mfma_f32_16x16x32_bf16(vh0, kl1, acc[1], 0, 0, 0);
        acc[1] = __builtin_amdgcn_mfma_f32_16x16x32_bf16(vl0, kh1, acc[1], 0, 0, 0);
        acc[2] = __builtin_amdgcn_mfma_f32_16x16x32_bf16(vh1, kh0, acc[2], 0, 0, 0);
        acc[2] = __builtin_amdgcn_mfma_f32_16x16x32_bf16(vh1, kl0, acc[2], 0, 0, 0);
        acc[2] = __builtin_amdgcn_mfma_f32_16x16x32_bf16(vl1, kh0, acc[2], 0, 0, 0);
        acc[3] = __builtin_amdgcn_mfma_f32_16x16x32_bf16(vh1, kh1, acc[3], 0, 0, 0);
        acc[3] = __builtin_amdgcn_mfma_f32_16x16x32_bf16(vh1, kl1, acc[3], 0, 0, 0);
        acc[3] = __builtin_amdgcn_mfma_f32_16x16x32_bf16(vl1, kh1, acc[3], 0, 0, 0);
      }
    }
  }

  // write partials (D layout: col = lm, row = lq*4 + r)
  if (wid < 2) {
    float* dst = (wid == 0 ? Gp : Mp) + (size_t)(c * 64 + bh) * 1024;
#pragma unroll
    for (int t = 0; t < 4; t++) {
      int i0 = (t >> 1) * 16, j0 = (t & 1) * 16;
#pragma unroll
      for (int r = 0; r < 4; r++)
        dst[(i0 + lq * 4 + r) * 32 + j0 + lm] = acc[t][r];
    }
  } else {
    float* dst = Cp + (size_t)(c * 64 + bh) * 2048;
#pragma unroll
    for (int t = 0; t < 4; t++) {
      int d0 = (wid - 2) * 32 + (t >> 1) * 16, j0 = (t & 1) * 16;
#pragma unroll
      for (int r = 0; r < 4; r++)
        dst[(d0 + lq * 4 + r) * 32 + j0 + lm] = acc[t][r];
    }
  }
}

// ------- per-(b,h) operator: chol, G^{-1}, A_w, sigma, F = Cv*Gi*(s*M*Gi)^4 -------
// Tri-solves are register-resident (lane = column, fully unrolled -> no LDS
// write->read turnaround on the serial chain); Gi and L^{-1}M solves run
// CONCURRENTLY on wave0/wave1. Arithmetic order identical to block version.
__global__ __launch_bounds__(256) void solve_op_k(
    const float* __restrict__ Gp, const float* __restrict__ Mp,
    const float* __restrict__ Cp, const float* __restrict__ lridge,
    const float* __restrict__ lgamma, float* __restrict__ Ft) {
  __shared__ float Gs[32 * 33];
  __shared__ float Ms[32 * 32];
  __shared__ float Gi[32 * 32];
  __shared__ float W2s[32 * 33];
  __shared__ float Aw[32 * 33];
  __shared__ float Nn[32 * 32];
  __shared__ float N2[32 * 32];
  __shared__ float T1[32 * 32];
  __shared__ float Cs[64 * 32];
  __shared__ float red[256];
  const int bh = blockIdx.x;
  const int tid = threadIdx.x;
  const float ridge = expf(lridge[0]);

  for (int e = tid; e < 1024; e += 256) {
    int i = e >> 5, j = e & 31;
    float g = 0.f, m = 0.f;
#pragma unroll
    for (int cc = 0; cc < TCH; cc++) {
      g += Gp[(size_t)(cc * 64 + bh) * 1024 + e];
      m += Mp[(size_t)(cc * 64 + bh) * 1024 + e];
    }
    if (i == j) g += ridge;
    Gs[i * 33 + j] = g;
    Ms[e] = m;
  }
  for (int e = tid; e < 2048; e += 256) {
    float s = 0.f;
#pragma unroll
    for (int cc = 0; cc < TCH; cc++) s += Cp[(size_t)(cc * 64 + bh) * 2048 + e];
    Cs[e] = s;
  }
  __syncthreads();

  for (int j = 0; j < 32; j++) {
    float d = Gs[j * 33 + j];
    __syncthreads();
    float inv = 1.0f / sqrtf(d);
    if (tid >= j && tid < 32) Gs[tid * 33 + j] *= inv;
    __syncthreads();
    int w = 31 - j;
    for (int e = tid; e < w * w; e += 256) {
      int i = j + 1 + e / w, k = j + 1 + e % w;
      Gs[i * 33 + k] -= Gs[i * 33 + j] * Gs[k * 33 + j];
    }
    __syncthreads();
  }

  // wave0: Gi = G^{-1} (fwd+back on e_c); wave1: W2 = L^{-1} M (fwd). Concurrent.
  if (tid < 32) {
    const int c = tid;
    float w[32];
#pragma unroll
    for (int i = 0; i < 32; i++) {
      float s = (i == c) ? 1.0f : 0.0f;
#pragma unroll
      for (int j = 0; j < 32; j++)
        if (j < i) s -= Gs[i * 33 + j] * w[j];
      w[i] = s / Gs[i * 33 + i];
    }
#pragma unroll
    for (int i = 31; i >= 0; i--) {
      float s = w[i];
#pragma unroll
      for (int j = 0; j < 32; j++)
        if (j > i) s -= Gs[j * 33 + i] * w[j];
      w[i] = s / Gs[i * 33 + i];
    }
#pragma unroll
    for (int i = 0; i < 32; i++) Gi[i * 32 + c] = w[i];
  } else if (tid >= 64 && tid < 96) {
    const int c = tid - 64;
    float w[32];
#pragma unroll
    for (int i = 0; i < 32; i++) {
      float s = Ms[i * 32 + c];
#pragma unroll
      for (int j = 0; j < 32; j++)
        if (j < i) s -= Gs[i * 33 + j] * w[j];
      w[i] = s / Gs[i * 33 + i];
    }
#pragma unroll
    for (int i = 0; i < 32; i++) W2s[i * 33 + c] = w[i];
  }
  __syncthreads();
  // Aw (holds A_w^T; only norms consumed): column c solves L a = (L^{-1}M) row c
  if (tid < 32) {
    const int c = tid;
    float a[32];
#pragma unroll
    for (int i = 0; i < 32; i++) {
      float s = W2s[c * 33 + i];
#pragma unroll
      for (int j = 0; j < 32; j++)
        if (j < i) s -= Gs[i * 33 + j] * a[j];
      a[i] = s / Gs[i * 33 + i];
    }
#pragma unroll
    for (int i = 0; i < 32; i++) Aw[i * 33 + c] = a[i];
  }
  __syncthreads();

  float s0 = 0.0f;
  for (int e = tid; e < 1024; e += 256) {
    float a = Aw[(e >> 5) * 33 + (e & 31)];
    s0 += a * a;
  }
  red[tid] = s0;
  __syncthreads();
  for (int off = 128; off > 0; off >>= 1) {
    if (tid < off) red[tid] += red[tid + off];
    __syncthreads();
  }
  float frob2 = red[0];
  float sigma;
  if (frob2 <= 1.0f) {
    sigma = sqrtf(frob2);
  } else {
    // in-wave power iteration, LDS reads (no register arrays -> no spill risk)
    if (tid < 32) {
      const int i = tid;
      float v = 1.0f + 0.001f * (float)i;
      float sig = 0.0f, prev = -1.0f;
      for (int it = 0; it < 64; it++) {
        float u = 0.0f;
#pragma unroll
        for (int j = 0; j < 32; j++) u += Aw[i * 33 + j] * __shfl(v, j, 64);
        float n2 = u * u;
#pragma unroll
        for (int o = 16; o > 0; o >>= 1) n2 += __shfl_xor(n2, o, 64);
        u /= fmaxf(sqrtf(n2), 1e-30f);
        float vn = 0.0f;
#pragma unroll
        for (int j = 0; j < 32; j++) vn += Aw[j * 33 + i] * __shfl(u, j, 64);
        float m2 = vn * vn;
#pragma unroll
        for (int o = 16; o > 0; o >>= 1) m2 += __shfl_xor(m2, o, 64);
        sig = sqrtf(m2);
        v = vn / fmaxf(sig, 1e-30f);
        if (it >= 7 && fabsf(sig - prev) <= 1e-7f * sig) break;
        prev = sig;
      }
      if (i == 0) red[0] = sig;
    }
    __syncthreads();
    sigma = red[0];
  }
  float gamma_c = fminf(expf(lgamma[0]), 1.0f);
  float scale = gamma_c / fmaxf(fmaxf(sigma, 1e-8f), 1.0f);

  for (int e = tid; e < 1024; e += 256) {
    int i = e >> 5, c = e & 31;
    float s = 0;
#pragma unroll
    for (int k = 0; k < 32; k++) s += Ms[i * 32 + k] * Gi[k * 32 + c];
    Nn[e] = scale * s;
  }
  __syncthreads();
  for (int e = tid; e < 1024; e += 256) {
    int i = e >> 5, c = e & 31;
    float s = 0;
#pragma unroll
    for (int k = 0; k < 32; k++) s += Nn[i * 32 + k] * Nn[k * 32 + c];
    N2[e] = s;
  }
  __syncthreads();
  for (int e = tid; e < 1024; e += 256) {
    int i = e >> 5, c = e & 31;
    float s = 0;
#pragma unroll
    for (int k = 0; k < 32; k++) s += N2[i * 32 + k] * N2[k * 32 + c];
    Ms[e] = s;
  }
  __syncthreads();
  for (int e = tid; e < 1024; e += 256) {
    int i = e >> 5, c = e & 31;
    float s = 0;
#pragma unroll
    for (int k = 0; k < 32; k++) s += Gi[i * 32 + k] * Ms[k * 32 + c];
    T1[e] = s;
  }
  __syncthreads();
  for (int e = tid; e < 2048; e += 256) {
    int j = e >> 6, d = e & 63;
    float s = 0;
#pragma unroll
    for (int k = 0; k < 32; k++) s += Cs[d * 32 + k] * T1[k * 32 + j];
    Ft[(size_t)bh * 2048 + e] = s;
  }
}

// ------------- apply F^T per (head, 128-token chunk) -> full_hi (bf16) -------------
// FH written chunk-swizzled within 32-col groups: chunk2 ^= (row>>1)&3
// (matches prep swz=2; consumed by gemm_out's linear stage + swizzled ds_read).
__global__ __launch_bounds__(256) void apply_k(const float* __restrict__ Y1,
                                               const float* __restrict__ Ft,
                                               unsigned short* __restrict__ FH) {
  __shared__ float xs[128 * 32];
  const int h = blockIdx.y;
  const int r0 = blockIdx.x * 128;
  const int bh = (r0 >> 12) * NH + h;
  const int tid = threadIdx.x;
  const int d = tid & 63, t0 = tid >> 6;
  float fcol[32];
  const float* fb = &Ft[(size_t)bh * 2048 + d];
#pragma unroll
  for (int j = 0; j < 32; j++) fcol[j] = fb[j * 64];
  for (int e = tid; e < 1024; e += 256) {
    int row = e >> 3, j4 = (e & 7) << 2;
    *(float4*)&xs[row * 32 + j4] =
        *(const float4*)&Y1[((size_t)(r0 + row)) * 512 + h * 32 + j4];
  }
  __syncthreads();
  const int dq2 = (d >> 3) & 3, dhi = d & 32, dr = d & 7;
  for (int tl = t0; tl < 128; tl += 4) {
    float s = 0;
#pragma unroll
    for (int j = 0; j < 32; j++) s += xs[tl * 32 + j] * fcol[j];
    int col = h * 64 + dhi + ((dq2 ^ ((tl >> 1) & 3)) << 3) + dr;
    FH[((size_t)(r0 + tl)) * 1024 + col] = bf16_rne(s);
  }
}

// ------------- output GEMM (MFMA): out = sg * full @ Wo ; A=hi, B=hi+lo -------------
// 256x128 tile, ring of 4 BK=32 slots (128 KB), ONE barrier per 32-K step,
// counted vmcnt(8) certifies the NEXT slot (2-step lead), stage targets the slot
// freed by the previous step's barrier. Loads span phases (T3+T4); 32-MFMA
// bursts under setprio (T5); swizzled reads conflict-free (T2, 32-col groups).
// Accumulation order per output bit-identical to the BK=64 version.
__global__ __launch_bounds__(512) void gemm_out_k(
    const unsigned short* __restrict__ FH,
    const unsigned short* __restrict__ WThi, const unsigned short* __restrict__ WTlo,
    const float* __restrict__ alpha, float* __restrict__ out) {
  __shared__ __align__(16) unsigned short lds[65536];  // A 4x16KB | Bh 4x8KB | Bl 4x8KB
  int xx, yy, zz;
  xcd_swz(8, 64, xx, yy, zz);
  const int m0 = yy * 256;
  const int n0 = xx * 128;
  const int tid = threadIdx.x;
  const int lane = tid & 63;
  const int wid  = tid >> 6;                 // 0..7
  const int wm = (wid >> 1) * 64;            // 4 M-waves x 64 rows
  const int wn = (wid & 1) * 64;             // 2 N-waves x 64 cols
  const int lm = lane & 15, lq = lane >> 4;
  const int l4 = lane >> 2, c4 = (lane & 3) << 3;  // staging: 16 rows x 4 chunks/issue

  f4v acc[4][4];
#pragma unroll
  for (int i = 0; i < 4; i++)
#pragma unroll
    for (int j = 0; j < 4; j++) acc[i][j] = (f4v){0.f, 0.f, 0.f, 0.f};

  auto STAGE = [&](int s) {
    const int slot = s & 3;
    const int kt = s * 32;
#pragma unroll
    for (int i = 0; i < 2; i++) {            // A: 2 issues/wave (16 total)
      int iss = wid * 2 + i;
      gll16(&lds[slot * 8192 + iss * 512],
            &FH[(size_t)(m0 + iss * 16 + l4) * 1024 + kt + c4]);
    }
    gll16(&lds[32768 + slot * 4096 + wid * 512],   // Bh: 1 issue/wave
          &WThi[(size_t)(n0 + wid * 16 + l4) * 1024 + kt + c4]);
    gll16(&lds[49152 + slot * 4096 + wid * 512],   // Bl: 1 issue/wave
          &WTlo[(size_t)(n0 + wid * 16 + l4) * 1024 + kt + c4]);
  };

  STAGE(0); STAGE(1); STAGE(2);
  asm volatile("s_waitcnt vmcnt(8)" ::: "memory");   // slot 0 certified
  __builtin_amdgcn_s_barrier();

  for (int s = 0; s < 32; s++) {
    const int slot = s & 3;
    if (s < 29) STAGE(s + 3);                // writes slot (s-1)&3, freed last barrier
    s8v ah[4], bh[4], bl[4];
#pragma unroll
    for (int i = 0; i < 4; i++) {
      int rA = wm + i * 16 + lm;
      int rB = wn + i * 16 + lm;
      ah[i] = *(const s8v*)&lds[slot * 8192 + rA * 32 + ((lq ^ ((rA >> 1) & 3)) << 3)];
      bh[i] = *(const s8v*)&lds[32768 + slot * 4096 + rB * 32 + ((lq ^ ((rB >> 1) & 3)) << 3)];
      bl[i] = *(const s8v*)&lds[49152 + slot * 4096 + rB * 32 + ((lq ^ ((rB >> 1) & 3)) << 3)];
    }
    if (s < 29)       asm volatile("s_waitcnt vmcnt(8)" ::: "memory");  // certify slot s+1
    else if (s == 29) asm volatile("s_waitcnt vmcnt(4)" ::: "memory");
    else if (s == 30) asm volatile("s_waitcnt vmcnt(0)" ::: "memory");
    asm volatile("s_waitcnt lgkmcnt(0)" ::: "memory");
    __builtin_amdgcn_sched_barrier(0);
    __builtin_amdgcn_s_setprio(1);
#pragma unroll
    for (int mi = 0; mi < 4; mi++)
#pragma unroll
      for (int ni = 0; ni < 4; ni++) {
        acc[mi][ni] = __builtin_amdgcn_mfma_f32_16x16x32_bf16(ah[mi], bh[ni], acc[mi][ni], 0, 0, 0);
        acc[mi][ni] = __builtin_amdgcn_mfma_f32_16x16x32_bf16(ah[mi], bl[ni], acc[mi][ni], 0, 0, 0);
      }
    __builtin_amdgcn_s_setprio(0);
    __builtin_amdgcn_s_barrier();            // frees slot s; publishes slot s+1 cert
  }

  float sg = 1.0f / (1.0f + expf(-alpha[0]));
#pragma unroll
  for (int mi = 0; mi < 4; mi++)
#pragma unroll
    for (int r = 0; r < 4; r++) {
      size_t orow = (size_t)(m0 + wm + mi * 16 + lq * 4 + r);
#pragma unroll
      for (int ni = 0; ni < 4; ni++)
        out[orow * 1024 + n0 + wn + ni * 16 + lm] = sg * acc[mi][ni][r];
    }
}

extern "C" void kernel_launch(void* const* d_in, const int* in_sizes, int n_in,
                              void* d_out, int out_size, void* d_ws, size_t ws_size,
                              hipStream_t stream) {
  const float* X      = (const float*)d_in[0];
  const float* Wk     = (const float*)d_in[1];
  const float* Wq     = (const float*)d_in[2];
  const float* Wv     = (const float*)d_in[3];
  const float* Wo     = (const float*)d_in[4];
  const float* lng    = (const float*)d_in[5];
  const float* lnb    = (const float*)d_in[6];
  const float* alpha  = (const float*)d_in[7];
  const float* lridge = (const float*)d_in[8];
  const float* lgamma = (const float*)d_in[9];
  const int*   pref   = (const int*)d_in[10];
  float* out = (float*)d_out;
  char* ws = (char*)d_ws;
  float* stats = (float*)(ws + OFF_STATS);
  float* Gp    = (float*)(ws + OFF_GP);
  float* Mp    = (float*)(ws + OFF_MP);
  float* Cp    = (float*)(ws + OFF_CP);
  float* Ft    = (float*)(ws + OFF_FT);
  unsigned short* WKH = (unsigned short*)(ws + OFF_WKH);
  unsigned short* WKL = (unsigned short*)(ws + OFF_WKL);
  unsigned short* WQH = (unsigned short*)(ws + OFF_WQH);
  unsigned short* WQL = (unsigned short*)(ws + OFF_WQL);
  unsigned short* WVH = (unsigned short*)(ws + OFF_WVH);
  unsigned short* WVL = (unsigned short*)(ws + OFF_WVL);
  unsigned short* WOH = (unsigned short*)(ws + OFF_WOH);
  unsigned short* WOL = (unsigned short*)(ws + OFF_WOL);
  float* Y1 = (float*)(ws + OFF_Y1);
  float* Y2 = (float*)(ws + OFF_Y2);
  unsigned short* FH = (unsigned short*)(ws + OFF_FH);

  ln_stats_k<<<16384, 256, 0, stream>>>(X, stats);
  prep_w_k<<<dim3(16, 32), 256, 0, stream>>>(Wk, 512, WKH, WKL, 2);
  prep_w_k<<<dim3(16, 32), 256, 0, stream>>>(Wq, 512, WQH, WQL, 2);
  prep_w_k<<<dim3(32, 32), 256, 0, stream>>>(Wv, 1024, WVH, WVL, 2);
  prep_w_k<<<dim3(32, 32), 256, 0, stream>>>(Wo, 1024, WOH, WOL, 2);
  gemm_ln_k<<<dim3(2, 32, NB), 512, 0, stream>>>(X, stats, lng, lnb,
      WKH, WKL, WQH, WQL, pref, 0, 512, Y1);
  gemm_ln_k<<<dim3(4, 32, NB), 512, 0, stream>>>(X, stats, lng, lnb,
      WVH, WVL, WVH, WVL, pref, 2, 1024, Y2);
  build_gmc_mfma_k<<<dim3(TCH, 64), 256, 0, stream>>>(Y1, Y2, pref, Gp, Mp, Cp);
  solve_op_k<<<64, 256, 0, stream>>>(Gp, Mp, Cp, lridge, lgamma, Ft);
  apply_k<<<dim3(128, NH), 256, 0, stream>>>(Y1, Ft, FH);
  gemm_out_k<<<dim3(8, 64), 512, 0, stream>>>(FH, WOH, WOL, alpha, out);
}